// Round 8
// baseline (197.747 us; speedup 1.0000x reference)
//
#include <hip/hip_runtime.h>
#include <math.h>

#define B_ 4
#define C_ 128
#define N_ 4096
#define NSPLIT 4
#define MT 32     // keys per iteration
#define HLD 136   // gnqkv h-tile row stride (shorts)

typedef float floatx4 __attribute__((ext_vector_type(4)));
typedef short bf16x8 __attribute__((ext_vector_type(8)));
typedef short bf16x4 __attribute__((ext_vector_type(4)));

__device__ __forceinline__ ushort f2bf(float f) {  // RNE
  unsigned u = __float_as_uint(f);
  return (ushort)((u + 0x7FFF + ((u >> 16) & 1)) >> 16);
}
__device__ __forceinline__ float bf2f(ushort u) {
  return __uint_as_float(((unsigned)u) << 16);
}
// pack two floats -> (hi16(a)<<16)|hi16(b), round-half-up
__device__ __forceinline__ unsigned pkbf(float a, float b) {
  return __builtin_amdgcn_perm(__float_as_uint(a) + 0x8000u,
                               __float_as_uint(b) + 0x8000u, 0x07060302u);
}
// async global -> LDS, 16B per lane; LDS dest = uniform base + lane*16
__device__ __forceinline__ void gl2lds16(const ushort* g, ushort* l) {
  __builtin_amdgcn_global_load_lds(
      (const __attribute__((address_space(1))) void*)g,
      (__attribute__((address_space(3))) void*)l, 16, 0, 0);
}

// ---------------- fused: gn_stats (blocks 0..255) + weight cvt (256..511) ----------------
__global__ __launch_bounds__(256) void prep_kernel(
    const float* __restrict__ x, float* __restrict__ gstat,
    const float* __restrict__ wq, const float* __restrict__ wk,
    const float* __restrict__ wv, const float* __restrict__ wp,
    ushort* __restrict__ wB) {
  if (blockIdx.x >= 256) {   // weight convert: 65536 elems
    int i = (blockIdx.x - 256) * 256 + threadIdx.x;
    int m = i >> 14, j = i & 16383;
    const float* src = (m == 0) ? wq : (m == 1) ? wk : (m == 2) ? wv : wp;
    wB[i] = f2bf(src[j]);
    return;
  }
  int b = blockIdx.x >> 6, g = (blockIdx.x >> 3) & 7, part = blockIdx.x & 7;
  const float4* xp = (const float4*)(x + (size_t)(b * C_ + g * 16) * N_) + part * 2048;
  float s = 0.f, ss = 0.f;
  for (int i = threadIdx.x; i < 2048; i += 256) {
    float4 v = xp[i];
    s += v.x + v.y + v.z + v.w;
    ss += v.x * v.x + v.y * v.y + v.z * v.z + v.w * v.w;
  }
  #pragma unroll
  for (int o = 32; o > 0; o >>= 1) {
    s += __shfl_down(s, o, 64);
    ss += __shfl_down(ss, o, 64);
  }
  __shared__ float rs[4], rss[4];
  int wid = threadIdx.x >> 6, lane = threadIdx.x & 63;
  if (lane == 0) { rs[wid] = s; rss[wid] = ss; }
  __syncthreads();
  if (threadIdx.x == 0) {
    int slot = (b * 8 + g) * 8 + part;
    gstat[slot]       = rs[0] + rs[1] + rs[2] + rs[3];
    gstat[256 + slot] = rss[0] + rss[1] + rss[2] + rss[3];
  }
}

// ---------------- fused GN-apply + QKV MFMA: grid 512 = (b, 32-n tile) ----------------
__global__ __launch_bounds__(256) void gnqkv_kernel(
    const float* __restrict__ x, const float* __restrict__ gstat,
    const float* __restrict__ scale, const float* __restrict__ bias,
    const ushort* __restrict__ wB,
    const float* __restrict__ bq, const float* __restrict__ bk,
    const float* __restrict__ bv,
    ushort* __restrict__ qT, ushort* __restrict__ kT, ushort* __restrict__ vB) {
  __shared__ __align__(16) ushort hs[32][HLD];
  __shared__ float sSc[C_], sBi[C_];
  int tid = threadIdx.x;
  int b = blockIdx.x >> 7;
  int n0 = (blockIdx.x & 127) * 32;
  if (tid < 128) {
    int g = tid >> 4;
    float S = 0.f, SS = 0.f;
    #pragma unroll
    for (int p = 0; p < 8; ++p) {
      S  += gstat[(b * 8 + g) * 8 + p];
      SS += gstat[256 + (b * 8 + g) * 8 + p];
    }
    float mu = S * (1.f / 65536.f);
    float var = SS * (1.f / 65536.f) - mu * mu;
    float rstd = rsqrtf(var + 1e-6f);
    float sc = scale[tid] * rstd;
    sSc[tid] = sc;
    sBi[tid] = bias[tid] - mu * sc;
  }
  __syncthreads();
  for (int i = tid; i < 1024; i += 256) {   // 128 c x 8 float4 (32 n)
    int c = i >> 3, n4 = i & 7;
    float4 v = *(const float4*)(x + (size_t)(b * C_ + c) * N_ + n0 + n4 * 4);
    float sc = sSc[c], bi = sBi[c];
    hs[n4 * 4 + 0][c] = f2bf(v.x * sc + bi);
    hs[n4 * 4 + 1][c] = f2bf(v.y * sc + bi);
    hs[n4 * 4 + 2][c] = f2bf(v.z * sc + bi);
    hs[n4 * 4 + 3][c] = f2bf(v.w * sc + bi);
  }
  __syncthreads();
  int lane = tid & 63, w = tid >> 6;
  int col = lane & 15, quad = lane >> 4;
  int nl = (w & 1) * 16 + col;
  int n = n0 + nl;
  int oh = (w >> 1) * 64;
  bf16x8 hf[4];
  #pragma unroll
  for (int kc = 0; kc < 4; ++kc)
    hf[kc] = *(const bf16x8*)&hs[nl][kc * 32 + quad * 8];
  const ushort* Wq = wB;
  const ushort* Wk = wB + 16384;
  const ushort* Wv = wB + 32768;
  const float scl = 0.12751879752224991f;  // 128^-0.5 * log2(e)
  #pragma unroll
  for (int ot = 0; ot < 4; ++ot) {
    int o0 = oh + ot * 16;
    floatx4 aq = (floatx4)0.f, ak = (floatx4)0.f, av = (floatx4)0.f;
    #pragma unroll
    for (int kc = 0; kc < 4; ++kc) {
      int wo = (o0 + col) * C_ + kc * 32 + quad * 8;
      aq = __builtin_amdgcn_mfma_f32_16x16x32_bf16(*(const bf16x8*)&Wq[wo], hf[kc], aq, 0, 0, 0);
      ak = __builtin_amdgcn_mfma_f32_16x16x32_bf16(*(const bf16x8*)&Wk[wo], hf[kc], ak, 0, 0, 0);
      av = __builtin_amdgcn_mfma_f32_16x16x32_bf16(*(const bf16x8*)&Wv[wo], hf[kc], av, 0, 0, 0);
    }
    float4 bqv = *(const float4*)&bq[o0 + quad * 4];
    float4 bkv = *(const float4*)&bk[o0 + quad * 4];
    float4 bvv = *(const float4*)&bv[o0 + quad * 4];
    uint2 qs = { pkbf((aq[1] + bqv.y) * scl, (aq[0] + bqv.x) * scl),
                 pkbf((aq[3] + bqv.w) * scl, (aq[2] + bqv.z) * scl) };
    uint2 ks = { pkbf(ak[1] + bkv.y, ak[0] + bkv.x),
                 pkbf(ak[3] + bkv.w, ak[2] + bkv.z) };
    *(uint2*)(qT + ((size_t)b * N_ + n) * C_ + o0 + quad * 4) = qs;
    *(uint2*)(kT + ((size_t)b * N_ + n) * C_ + o0 + quad * 4) = ks;
    float vv[4] = {av[0] + bvv.x, av[1] + bvv.y, av[2] + bvv.z, av[3] + bvv.w};
    #pragma unroll
    for (int r = 0; r < 4; ++r)
      vB[((size_t)b * C_ + o0 + quad * 4 + r) * N_ + n] = f2bf(vv[r]);
  }
}

// ---------------- MFMA flash attention: no-max softmax, P in registers ----------------
// grid 1024: sp=bx&3, qblk=(bx>>2)&63, b=bx>>8.  256 thr = 4 waves x 16 q-rows
__global__ __launch_bounds__(256, 4) void attn_kernel(
    const ushort* __restrict__ qT, const ushort* __restrict__ kT,
    const ushort* __restrict__ vB, ushort* __restrict__ Op,
    float* __restrict__ Lv) {
  __shared__ __align__(16) ushort Ks[2][MT * 128];   // 2 x 8 KB (chunk-swizzled by row&7)
  __shared__ __align__(16) ushort Vs[2][C_ * MT];    // 2 x 8 KB (chunk-swizzled by c&3)
  int sp = blockIdx.x & 3;
  int qblk = (blockIdx.x >> 2) & 63;
  int b = blockIdx.x >> 8;
  int n0 = qblk * 64;
  int tid = threadIdx.x, lane = tid & 63, w = tid >> 6;
  int col = lane & 15, quad = lane >> 4;
  int wu = __builtin_amdgcn_readfirstlane(w);
  const ushort* kTb = kT + (size_t)b * N_ * C_;
  const ushort* vBb = vB + (size_t)b * C_ * N_;

  bf16x8 qf[4];   // Q B-frags for this wave's 16 q-rows (direct from global, L2-hot)
  #pragma unroll
  for (int kc = 0; kc < 4; ++kc)
    qf[kc] = *(const bf16x8*)(qT + ((size_t)b * N_ + n0 + w * 16 + col) * C_ + kc * 32 + quad * 8);

  floatx4 Oacc[8];
  #pragma unroll
  for (int ct = 0; ct < 8; ++ct) Oacc[ct] = (floatx4)0.f;
  float lrun = 0.f;

  // K: 32 rows x 256B; LDS pos p of row r holds chunk p^(r&7).
  // V: 128 rows x 64B;  LDS pos p of row c holds chunk p^(c&3).
  #define STAGE(m0v, buf)                                                              \
    {                                                                                  \
      _Pragma("unroll")                                                                \
      for (int j = 0; j < 2; ++j) {                                                    \
        int inst = wu * 2 + j;                                                         \
        int r = inst * 4 + (lane >> 4);                                                \
        int pos = (lane & 15) ^ (r & 7);                                               \
        gl2lds16(kTb + (size_t)((m0v) + r) * 128 + pos * 8, &Ks[buf][inst * 512]);     \
      }                                                                                \
      _Pragma("unroll")                                                                \
      for (int j = 0; j < 2; ++j) {                                                    \
        int inst = wu * 2 + j;                                                         \
        int c = inst * 16 + (lane >> 2);                                               \
        int pos = (lane & 3) ^ (c & 3);                                                \
        gl2lds16(vBb + (size_t)c * N_ + (m0v) + pos * 8, &Vs[buf][inst * 512]);        \
      }                                                                                \
    }

  STAGE(sp * 1024, 0);
  __syncthreads();

  for (int it = 0; it < 1024 / MT; ++it) {
    if (it < 1024 / MT - 1) STAGE(sp * 1024 + (it + 1) * MT, (it + 1) & 1);
    const ushort* KsB = Ks[it & 1];
    const ushort* VsB = Vs[it & 1];

    // S^T = K·Q^T per 16-m tile (rows m in-register, cols q)
    floatx4 st[2];
    #pragma unroll
    for (int mt = 0; mt < 2; ++mt) {
      int row = mt * 16 + col;
      bf16x8 kf[4];
      #pragma unroll
      for (int kc = 0; kc < 4; ++kc)
        kf[kc] = *(const bf16x8*)&KsB[row * 128 + (((4 * kc + quad) ^ (col & 7)) * 8)];
      floatx4 acc = (floatx4)0.f;
      #pragma unroll
      for (int kc = 0; kc < 4; ++kc)
        acc = __builtin_amdgcn_mfma_f32_16x16x32_bf16(kf[kc], qf[kc], acc, 0, 0, 0);
      st[mt] = acc;
    }
    // no-max softmax (inputs bounded: |S_log2| << 127): p = exp2(S), l += sum
    float p[2][4];
    float lsum = 0.f;
    #pragma unroll
    for (int mt = 0; mt < 2; ++mt)
      #pragma unroll
      for (int r = 0; r < 4; ++r) {
        p[mt][r] = exp2f(st[mt][r]);
        lsum += p[mt][r];
      }
    lsum += __shfl_xor(lsum, 16, 64);
    lsum += __shfl_xor(lsum, 32, 64);
    lrun += lsum;
    // PV via x16 MFMA: P C-layout (m=quad*4+r) == x16 A-layout (k=quad*4+j)
    union PF { unsigned u[2]; bf16x4 s; } pf[2];
    #pragma unroll
    for (int mt = 0; mt < 2; ++mt) {
      pf[mt].u[0] = pkbf(p[mt][1], p[mt][0]);
      pf[mt].u[1] = pkbf(p[mt][3], p[mt][2]);
    }
    #pragma unroll
    for (int ct = 0; ct < 8; ++ct) {
      int cc = ct * 16 + col;
      #pragma unroll
      for (int mt = 0; mt < 2; ++mt) {
        int pc = (mt * 2 + (quad >> 1)) ^ (cc & 3);
        bf16x4 vf = *(const bf16x4*)&VsB[cc * 32 + pc * 8 + (quad & 1) * 4];
        Oacc[ct] = __builtin_amdgcn_mfma_f32_16x16x16bf16_1k(pf[mt].s, vf, Oacc[ct], 0, 0, 0);
      }
    }
    __syncthreads();   // drains prefetch (vmcnt) + gates dbuf reuse
  }

  // epilogue: Op[sp][b][n][c] bf16 (unnormalized) + l
  ushort* OpB = Op + (((size_t)sp * B_ + b) * N_ + n0 + w * 16) * C_;
  #pragma unroll
  for (int ct = 0; ct < 8; ++ct)
    #pragma unroll
    for (int r = 0; r < 4; ++r)
      OpB[(size_t)(quad * 4 + r) * C_ + ct * 16 + col] = f2bf(Oacc[ct][r]);
  if (quad == 0) {
    int idx = b * N_ + n0 + w * 16 + col;
    Lv[(size_t)sp * (B_ * N_) + idx] = lrun;
  }
}

// ---------------- fused merge(4 splits, no-max) + proj MFMA + residual ----------------
__global__ __launch_bounds__(256) void mergeproj_kernel(
    const ushort* __restrict__ Op, const float* __restrict__ Lv,
    const ushort* __restrict__ wpB, const float* __restrict__ bp,
    const float* __restrict__ x, float* __restrict__ out) {
  int tid = threadIdx.x, lane = tid & 63, w = tid >> 6;
  int col = lane & 15, quad = lane >> 4;
  int b = blockIdx.x >> 7;
  int n = (blockIdx.x & 127) * 32 + (w & 1) * 16 + col;
  int oh = (w >> 1) * 64;
  int nIdx = b * N_ + n;
  float den = 0.f;
  #pragma unroll
  for (int sp = 0; sp < NSPLIT; ++sp) den += Lv[sp * (B_ * N_) + nIdx];
  float inv = 1.f / den;
  bf16x8 hf[4];
  #pragma unroll
  for (int kc = 0; kc < 4; ++kc) {
    float o[8];
    #pragma unroll
    for (int j = 0; j < 8; ++j) o[j] = 0.f;
    #pragma unroll
    for (int sp = 0; sp < NSPLIT; ++sp) {
      uint4 d = *(const uint4*)&Op[((size_t)sp * (B_ * N_) + nIdx) * C_ + kc * 32 + quad * 8];
      unsigned dd[4] = {d.x, d.y, d.z, d.w};
      #pragma unroll
      for (int j = 0; j < 4; ++j) {
        o[j * 2]     += bf2f((ushort)(dd[j] & 0xFFFF));
        o[j * 2 + 1] += bf2f((ushort)(dd[j] >> 16));
      }
    }
    union HF { unsigned u[4]; bf16x8 s; } hfu;
    #pragma unroll
    for (int j = 0; j < 4; ++j)
      hfu.u[j] = pkbf(o[j * 2 + 1] * inv, o[j * 2] * inv);
    hf[kc] = hfu.s;
  }
  #pragma unroll
  for (int ot = 0; ot < 4; ++ot) {
    int o0 = oh + ot * 16;
    floatx4 acc = (floatx4)0.f;
    #pragma unroll
    for (int kc = 0; kc < 4; ++kc) {
      int wo = (o0 + col) * C_ + kc * 32 + quad * 8;
      acc = __builtin_amdgcn_mfma_f32_16x16x32_bf16(*(const bf16x8*)&wpB[wo], hf[kc], acc, 0, 0, 0);
    }
    float4 bpv = *(const float4*)&bp[o0 + quad * 4];
    float bb[4] = {bpv.x, bpv.y, bpv.z, bpv.w};
    #pragma unroll
    for (int r = 0; r < 4; ++r) {
      size_t idx = ((size_t)b * C_ + o0 + quad * 4 + r) * N_ + n;
      out[idx] = acc[r] + bb[r] + x[idx];
    }
  }
}

extern "C" void kernel_launch(void* const* d_in, const int* in_sizes, int n_in,
                              void* d_out, int out_size, void* d_ws, size_t ws_size,
                              hipStream_t stream) {
  const float* x        = (const float*)d_in[0];
  const float* gn_scale = (const float*)d_in[1];
  const float* gn_bias  = (const float*)d_in[2];
  const float* wq = (const float*)d_in[3];
  const float* bq = (const float*)d_in[4];
  const float* wk = (const float*)d_in[5];
  const float* bk = (const float*)d_in[6];
  const float* wv = (const float*)d_in[7];
  const float* bv = (const float*)d_in[8];
  const float* wp = (const float*)d_in[9];
  const float* bp = (const float*)d_in[10];
  float* out = (float*)d_out;

  // workspace map (32 MB):
  // [0,256K) unused | [256K,512K) Lv | [512K,640K) wB (4x32KB bf16) | [640K,+2KB) gstat
  // [4M,8M) qT | [8M,12M) kT | [12M,16M) vB | [16M,32M) Op[4][B][N][C] bf16
  char* ws = (char*)d_ws;
  float*  Lv    = (float*)(ws + 262144);
  ushort* wB    = (ushort*)(ws + 524288);
  float*  gstat = (float*)(ws + 655360);
  ushort* qT    = (ushort*)(ws + (4u << 20));
  ushort* kT    = (ushort*)(ws + (8u << 20));
  ushort* vB    = (ushort*)(ws + (12u << 20));
  ushort* Op    = (ushort*)(ws + (16u << 20));
  ushort* wpB   = wB + 49152;

  prep_kernel<<<512, 256, 0, stream>>>(x, gstat, wq, wk, wv, wp, wB);
  gnqkv_kernel<<<512, 256, 0, stream>>>(x, gstat, gn_scale, gn_bias, wB, bq, bk, bv, qT, kT, vB);
  attn_kernel<<<1024, 256, 0, stream>>>(qT, kT, vB, Op, Lv);
  mergeproj_kernel<<<512, 256, 0, stream>>>(Op, Lv, wpB, bp, x, out);
}

// Round 10
// 161.307 us; speedup vs baseline: 1.2259x; 1.2259x over previous
//
#include <hip/hip_runtime.h>
#include <math.h>

#define B_ 4
#define C_ 128
#define N_ 4096
#define NSPLIT 4
#define MT 32     // keys per iteration
#define PLD 40    // Ps row stride (shorts): 32 + 8 pad
#define HLD 136   // h/q/k tile row stride (shorts): 128 + 8 pad
#define VTLD 48   // gnqkv v-tile row stride (shorts): 32 + 16 pad (96 B = 6x16 ✓ alignment)

typedef float floatx4 __attribute__((ext_vector_type(4)));
typedef short bf16x8 __attribute__((ext_vector_type(8)));

__device__ __forceinline__ ushort f2bf(float f) {  // RNE
  unsigned u = __float_as_uint(f);
  return (ushort)((u + 0x7FFF + ((u >> 16) & 1)) >> 16);
}
__device__ __forceinline__ float bf2f(ushort u) {
  return __uint_as_float(((unsigned)u) << 16);
}
// pack two floats -> (hi16(a)<<16)|hi16(b), round-half-up
__device__ __forceinline__ unsigned pkbf(float a, float b) {
  return __builtin_amdgcn_perm(__float_as_uint(a) + 0x8000u,
                               __float_as_uint(b) + 0x8000u, 0x07060302u);
}
// async global -> LDS, 16B per lane; LDS dest = uniform base + lane*16
__device__ __forceinline__ void gl2lds16(const ushort* g, ushort* l) {
  __builtin_amdgcn_global_load_lds(
      (const __attribute__((address_space(1))) void*)g,
      (__attribute__((address_space(3))) void*)l, 16, 0, 0);
}

// ---------------- fused: gn_stats (blocks 0..255) + weight cvt (256..511) ----------------
__global__ __launch_bounds__(256) void prep_kernel(
    const float* __restrict__ x, float* __restrict__ gstat,
    const float* __restrict__ wq, const float* __restrict__ wk,
    const float* __restrict__ wv, const float* __restrict__ wp,
    ushort* __restrict__ wB) {
  if (blockIdx.x >= 256) {   // weight convert: 65536 elems
    int i = (blockIdx.x - 256) * 256 + threadIdx.x;
    int m = i >> 14, j = i & 16383;
    const float* src = (m == 0) ? wq : (m == 1) ? wk : (m == 2) ? wv : wp;
    wB[i] = f2bf(src[j]);
    return;
  }
  int b = blockIdx.x >> 6, g = (blockIdx.x >> 3) & 7, part = blockIdx.x & 7;
  const float4* xp = (const float4*)(x + (size_t)(b * C_ + g * 16) * N_) + part * 2048;
  float s = 0.f, ss = 0.f;
  for (int i = threadIdx.x; i < 2048; i += 256) {
    float4 v = xp[i];
    s += v.x + v.y + v.z + v.w;
    ss += v.x * v.x + v.y * v.y + v.z * v.z + v.w * v.w;
  }
  #pragma unroll
  for (int o = 32; o > 0; o >>= 1) {
    s += __shfl_down(s, o, 64);
    ss += __shfl_down(ss, o, 64);
  }
  __shared__ float rs[4], rss[4];
  int wid = threadIdx.x >> 6, lane = threadIdx.x & 63;
  if (lane == 0) { rs[wid] = s; rss[wid] = ss; }
  __syncthreads();
  if (threadIdx.x == 0) {
    int slot = (b * 8 + g) * 8 + part;
    gstat[slot]       = rs[0] + rs[1] + rs[2] + rs[3];
    gstat[256 + slot] = rss[0] + rss[1] + rss[2] + rss[3];
  }
}

// ---------------- fused GN-apply + QKV MFMA, LDS-staged coalesced stores ----------------
// grid 512 = (b, 32-n tile), 256 thr
__global__ __launch_bounds__(256) void gnqkv_kernel(
    const float* __restrict__ x, const float* __restrict__ gstat,
    const float* __restrict__ scale, const float* __restrict__ bias,
    const ushort* __restrict__ wB,
    const float* __restrict__ bq, const float* __restrict__ bk,
    const float* __restrict__ bv,
    ushort* __restrict__ qT, ushort* __restrict__ kT, ushort* __restrict__ vB) {
  __shared__ __align__(16) ushort hs[32][HLD];
  __shared__ __align__(16) ushort Qt[32][HLD];
  __shared__ __align__(16) ushort Kt[32][HLD];
  __shared__ __align__(16) ushort Vt[128][VTLD];
  __shared__ float sSc[C_], sBi[C_];
  int tid = threadIdx.x;
  int b = blockIdx.x >> 7;
  int n0 = (blockIdx.x & 127) * 32;
  if (tid < 128) {
    int g = tid >> 4;
    float S = 0.f, SS = 0.f;
    #pragma unroll
    for (int p = 0; p < 8; ++p) {
      S  += gstat[(b * 8 + g) * 8 + p];
      SS += gstat[256 + (b * 8 + g) * 8 + p];
    }
    float mu = S * (1.f / 65536.f);
    float var = SS * (1.f / 65536.f) - mu * mu;
    float rstd = rsqrtf(var + 1e-6f);
    float sc = scale[tid] * rstd;
    sSc[tid] = sc;
    sBi[tid] = bias[tid] - mu * sc;
  }
  __syncthreads();
  for (int i = tid; i < 1024; i += 256) {   // 128 c x 8 float4 (32 n)
    int c = i >> 3, n4 = i & 7;
    float4 v = *(const float4*)(x + (size_t)(b * C_ + c) * N_ + n0 + n4 * 4);
    float sc = sSc[c], bi = sBi[c];
    hs[n4 * 4 + 0][c] = f2bf(v.x * sc + bi);
    hs[n4 * 4 + 1][c] = f2bf(v.y * sc + bi);
    hs[n4 * 4 + 2][c] = f2bf(v.z * sc + bi);
    hs[n4 * 4 + 3][c] = f2bf(v.w * sc + bi);
  }
  __syncthreads();
  int lane = tid & 63, w = tid >> 6;
  int col = lane & 15, quad = lane >> 4;
  int nl = (w & 1) * 16 + col;
  int oh = (w >> 1) * 64;
  bf16x8 hf[4];
  #pragma unroll
  for (int kc = 0; kc < 4; ++kc)
    hf[kc] = *(const bf16x8*)&hs[nl][kc * 32 + quad * 8];
  const ushort* Wq = wB;
  const ushort* Wk = wB + 16384;
  const ushort* Wv = wB + 32768;
  const float scl = 0.12751879752224991f;  // 128^-0.5 * log2(e)
  #pragma unroll
  for (int ot = 0; ot < 4; ++ot) {
    int o0 = oh + ot * 16;
    floatx4 aq = (floatx4)0.f, ak = (floatx4)0.f, av = (floatx4)0.f;
    #pragma unroll
    for (int kc = 0; kc < 4; ++kc) {
      int wo = (o0 + col) * C_ + kc * 32 + quad * 8;
      aq = __builtin_amdgcn_mfma_f32_16x16x32_bf16(*(const bf16x8*)&Wq[wo], hf[kc], aq, 0, 0, 0);
      ak = __builtin_amdgcn_mfma_f32_16x16x32_bf16(*(const bf16x8*)&Wk[wo], hf[kc], ak, 0, 0, 0);
      av = __builtin_amdgcn_mfma_f32_16x16x32_bf16(*(const bf16x8*)&Wv[wo], hf[kc], av, 0, 0, 0);
    }
    float4 bqv = *(const float4*)&bq[o0 + quad * 4];
    float4 bkv = *(const float4*)&bk[o0 + quad * 4];
    float4 bvv = *(const float4*)&bv[o0 + quad * 4];
    uint2 qs = { pkbf((aq[1] + bqv.y) * scl, (aq[0] + bqv.x) * scl),
                 pkbf((aq[3] + bqv.w) * scl, (aq[2] + bqv.z) * scl) };
    uint2 ks = { pkbf(ak[1] + bkv.y, ak[0] + bkv.x),
                 pkbf(ak[3] + bkv.w, ak[2] + bkv.z) };
    *(uint2*)&Qt[nl][o0 + quad * 4] = qs;
    *(uint2*)&Kt[nl][o0 + quad * 4] = ks;
    float vv[4] = {av[0] + bvv.x, av[1] + bvv.y, av[2] + bvv.z, av[3] + bvv.w};
    #pragma unroll
    for (int r = 0; r < 4; ++r)
      Vt[o0 + quad * 4 + r][nl] = f2bf(vv[r]);
  }
  __syncthreads();
  // coalesced stores
  #pragma unroll
  for (int k2 = 0; k2 < 2; ++k2) {   // q/k: 512 uint4 each
    int idx = tid + k2 * 256;
    int row = idx >> 4, seg = idx & 15;
    size_t dst = ((size_t)b * N_ + n0 + row) * C_ + seg * 8;
    *(uint4*)(qT + dst) = *(const uint4*)&Qt[row][seg * 8];
    *(uint4*)(kT + dst) = *(const uint4*)&Kt[row][seg * 8];
  }
  #pragma unroll
  for (int k2 = 0; k2 < 2; ++k2) {   // v: 512 uint4
    int idx = tid + k2 * 256;
    int o = idx >> 2, seg = idx & 3;
    *(uint4*)(vB + ((size_t)b * C_ + o) * N_ + n0 + seg * 8) = *(const uint4*)&Vt[o][seg * 8];
  }
}

// ---------------- MFMA flash attention: no-max softmax, x32 PV, dbuf staging ----------------
// grid 512: sp=bx&3, qblk=(bx>>2)&31, b=bx>>7.  256 thr = 4 waves x 32 q-rows
__global__ __launch_bounds__(256, 2) void attn_kernel(
    const ushort* __restrict__ qT, const ushort* __restrict__ kT,
    const ushort* __restrict__ vB, ushort* __restrict__ Op,
    float* __restrict__ Lv) {
  __shared__ __align__(16) ushort Ks[2][MT * 128];   // 2 x 8 KB (chunk-swizzled by row&7)
  __shared__ __align__(16) ushort Vs[2][C_ * MT];    // 2 x 8 KB
  __shared__ __align__(16) ushort Ps[128 * PLD];     // 10 KB
  int sp = blockIdx.x & 3;
  int qblk = (blockIdx.x >> 2) & 31;
  int b = blockIdx.x >> 7;
  int n0 = qblk * 128;
  int tid = threadIdx.x, lane = tid & 63, w = tid >> 6;
  int col = lane & 15, quad = lane >> 4;
  int wu = __builtin_amdgcn_readfirstlane(w);
  const ushort* kTb = kT + (size_t)b * N_ * C_;
  const ushort* vBb = vB + (size_t)b * C_ * N_;

  bf16x8 qf[2][4];   // Q B-frags for this wave's 32 q-rows (direct from global, L2-hot)
  #pragma unroll
  for (int qt = 0; qt < 2; ++qt)
    #pragma unroll
    for (int kc = 0; kc < 4; ++kc)
      qf[qt][kc] = *(const bf16x8*)(qT + ((size_t)b * N_ + n0 + w * 32 + qt * 16 + col) * C_ + kc * 32 + quad * 8);

  floatx4 Oacc[2][8];
  #pragma unroll
  for (int qt = 0; qt < 2; ++qt)
    #pragma unroll
    for (int ct = 0; ct < 8; ++ct) Oacc[qt][ct] = (floatx4)0.f;
  float lrun[2] = {0.f, 0.f};

  // K: 32 rows x 256B; LDS pos p of row r holds global chunk p^(r&7).
  // V: 128 rows x 64B; no swizzle.
  #define STAGE(m0v, buf)                                                              \
    {                                                                                  \
      _Pragma("unroll")                                                                \
      for (int j = 0; j < 2; ++j) {                                                    \
        int inst = wu * 2 + j;                                                         \
        int r = inst * 4 + (lane >> 4);                                                \
        int pos = (lane & 15) ^ (r & 7);                                               \
        gl2lds16(kTb + (size_t)((m0v) + r) * 128 + pos * 8, &Ks[buf][inst * 512]);     \
      }                                                                                \
      _Pragma("unroll")                                                                \
      for (int j = 0; j < 2; ++j) {                                                    \
        int inst = wu * 2 + j;                                                         \
        int c = inst * 16 + (lane >> 2);                                               \
        gl2lds16(vBb + (size_t)c * N_ + (m0v) + (lane & 3) * 8, &Vs[buf][inst * 512]); \
      }                                                                                \
    }

  STAGE(sp * 1024, 0);
  __syncthreads();

  for (int it = 0; it < 1024 / MT; ++it) {
    if (it < 1024 / MT - 1) STAGE(sp * 1024 + (it + 1) * MT, (it + 1) & 1);
    const ushort* KsB = Ks[it & 1];
    const ushort* VsB = Vs[it & 1];

    // S^T = K·Q^T per 16-m tile (rows m in-register, cols q)
    floatx4 st[2][2];
    #pragma unroll
    for (int mt = 0; mt < 2; ++mt) {
      int row = mt * 16 + col;
      bf16x8 kf[4];
      #pragma unroll
      for (int kc = 0; kc < 4; ++kc)
        kf[kc] = *(const bf16x8*)&KsB[row * 128 + (((4 * kc + quad) ^ (col & 7)) * 8)];
      #pragma unroll
      for (int qt = 0; qt < 2; ++qt) {
        floatx4 acc = (floatx4)0.f;
        #pragma unroll
        for (int kc = 0; kc < 4; ++kc)
          acc = __builtin_amdgcn_mfma_f32_16x16x32_bf16(kf[kc], qf[qt][kc], acc, 0, 0, 0);
        st[qt][mt] = acc;
      }
    }
    // no-max softmax (|S_log2| bounded ~9 << 127): p = exp2(S) directly off the MFMA.
    #pragma unroll
    for (int qt = 0; qt < 2; ++qt) {
      int prow = (w * 32 + qt * 16 + col) * PLD;
      float lsum = 0.f;
      #pragma unroll
      for (int mt = 0; mt < 2; ++mt) {
        float p0 = exp2f(st[qt][mt][0]);
        float p1 = exp2f(st[qt][mt][1]);
        float p2 = exp2f(st[qt][mt][2]);
        float p3 = exp2f(st[qt][mt][3]);
        uint2 pk = { pkbf(p1, p0), pkbf(p3, p2) };
        *(uint2*)&Ps[prow + mt * 16 + quad * 4] = pk;
        lsum += (p0 + p1) + (p2 + p3);
      }
      lsum += __shfl_xor(lsum, 16, 64);
      lsum += __shfl_xor(lsum, 32, 64);
      lrun[qt] += lsum;
    }
    // PV: A = P[q][m], B = V[c][m]
    bf16x8 pf[2];
    #pragma unroll
    for (int qt = 0; qt < 2; ++qt)
      pf[qt] = *(const bf16x8*)&Ps[(w * 32 + qt * 16 + col) * PLD + quad * 8];
    #pragma unroll
    for (int ct = 0; ct < 8; ++ct) {
      bf16x8 vf = *(const bf16x8*)&VsB[(ct * 16 + col) * MT + quad * 8];
      #pragma unroll
      for (int qt = 0; qt < 2; ++qt)
        Oacc[qt][ct] = __builtin_amdgcn_mfma_f32_16x16x32_bf16(pf[qt], vf, Oacc[qt][ct], 0, 0, 0);
    }
    __syncthreads();   // drains prefetch (vmcnt) + gates dbuf reuse
  }

  // epilogue: Op[sp][b][n][c] bf16 (unnormalized) + l
  ushort* OpB = Op + (((size_t)sp * B_ + b) * N_ + n0 + w * 32) * C_;
  #pragma unroll
  for (int qt = 0; qt < 2; ++qt)
    #pragma unroll
    for (int ct = 0; ct < 8; ++ct)
      #pragma unroll
      for (int r = 0; r < 4; ++r)
        OpB[(size_t)(qt * 16 + quad * 4 + r) * C_ + ct * 16 + col] = f2bf(Oacc[qt][ct][r]);
  if (quad == 0) {
    #pragma unroll
    for (int qt = 0; qt < 2; ++qt) {
      int idx = b * N_ + n0 + w * 32 + qt * 16 + col;
      Lv[(size_t)sp * (B_ * N_) + idx] = lrun[qt];
    }
  }
}

// ---------------- fused merge(4 splits, no-max) + proj MFMA + residual ----------------
// grid 512 = (b, 32-n tile); Op loads coalesced via LDS tile
__global__ __launch_bounds__(256) void mergeproj_kernel(
    const ushort* __restrict__ Op, const float* __restrict__ Lv,
    const ushort* __restrict__ wpB, const float* __restrict__ bp,
    const float* __restrict__ x, float* __restrict__ out) {
  __shared__ __align__(16) ushort tile[32 * HLD];
  int tid = threadIdx.x;
  int b = blockIdx.x >> 7;
  int n0 = (blockIdx.x & 127) * 32;
  {  // stage: thread owns (n = tid>>3); TWO uint4 chunks c8 and c8+8 -> all 128 channels
    int n = tid >> 3, c8 = tid & 7;
    int nIdx = b * N_ + n0 + n;
    float den = Lv[0 * (B_ * N_) + nIdx] + Lv[1 * (B_ * N_) + nIdx] +
                Lv[2 * (B_ * N_) + nIdx] + Lv[3 * (B_ * N_) + nIdx];
    float inv = 1.f / den;
    #pragma unroll
    for (int half = 0; half < 2; ++half) {
      int cc = c8 + half * 8;
      float o[8];
      #pragma unroll
      for (int j = 0; j < 8; ++j) o[j] = 0.f;
      #pragma unroll
      for (int sp = 0; sp < NSPLIT; ++sp) {
        uint4 d = *(const uint4*)&Op[((size_t)sp * (B_ * N_) + nIdx) * C_ + cc * 8];
        unsigned dd[4] = {d.x, d.y, d.z, d.w};
        #pragma unroll
        for (int j = 0; j < 4; ++j) {
          o[j * 2]     += bf2f((ushort)(dd[j] & 0xFFFF));
          o[j * 2 + 1] += bf2f((ushort)(dd[j] >> 16));
        }
      }
      uint4 res;
      res.x = pkbf(o[1] * inv, o[0] * inv);
      res.y = pkbf(o[3] * inv, o[2] * inv);
      res.z = pkbf(o[5] * inv, o[4] * inv);
      res.w = pkbf(o[7] * inv, o[6] * inv);
      *(uint4*)&tile[n * HLD + cc * 8] = res;
    }
  }
  __syncthreads();
  int lane = tid & 63, w = tid >> 6;
  int col = lane & 15, quad = lane >> 4;
  int nl = (w & 1) * 16 + col;
  int n = n0 + nl;
  int oh = (w >> 1) * 64;
  bf16x8 hf[4];
  #pragma unroll
  for (int kc = 0; kc < 4; ++kc)
    hf[kc] = *(const bf16x8*)&tile[nl * HLD + kc * 32 + quad * 8];
  #pragma unroll
  for (int ot = 0; ot < 4; ++ot) {
    int o0 = oh + ot * 16;
    floatx4 acc = (floatx4)0.f;
    #pragma unroll
    for (int kc = 0; kc < 4; ++kc) {
      int wo = (o0 + col) * C_ + kc * 32 + quad * 8;
      acc = __builtin_amdgcn_mfma_f32_16x16x32_bf16(*(const bf16x8*)&wpB[wo], hf[kc], acc, 0, 0, 0);
    }
    float4 bpv = *(const float4*)&bp[o0 + quad * 4];
    float bb[4] = {bpv.x, bpv.y, bpv.z, bpv.w};
    #pragma unroll
    for (int r = 0; r < 4; ++r) {
      size_t idx = ((size_t)b * C_ + o0 + quad * 4 + r) * N_ + n;
      out[idx] = acc[r] + bb[r] + x[idx];
    }
  }
}

extern "C" void kernel_launch(void* const* d_in, const int* in_sizes, int n_in,
                              void* d_out, int out_size, void* d_ws, size_t ws_size,
                              hipStream_t stream) {
  const float* x        = (const float*)d_in[0];
  const float* gn_scale = (const float*)d_in[1];
  const float* gn_bias  = (const float*)d_in[2];
  const float* wq = (const float*)d_in[3];
  const float* bq = (const float*)d_in[4];
  const float* wk = (const float*)d_in[5];
  const float* bk = (const float*)d_in[6];
  const float* wv = (const float*)d_in[7];
  const float* bv = (const float*)d_in[8];
  const float* wp = (const float*)d_in[9];
  const float* bp = (const float*)d_in[10];
  float* out = (float*)d_out;

  // workspace map (32 MB):
  // [256K,512K) Lv | [512K,640K) wB (4x32KB bf16) | [640K,+2KB) gstat
  // [4M,8M) qT | [8M,12M) kT | [12M,16M) vB | [16M,32M) Op[4][B][N][C] bf16
  char* ws = (char*)d_ws;
  float*  Lv    = (float*)(ws + 262144);
  ushort* wB    = (ushort*)(ws + 524288);
  float*  gstat = (float*)(ws + 655360);
  ushort* qT    = (ushort*)(ws + (4u << 20));
  ushort* kT    = (ushort*)(ws + (8u << 20));
  ushort* vB    = (ushort*)(ws + (12u << 20));
  ushort* Op    = (ushort*)(ws + (16u << 20));
  ushort* wpB   = wB + 49152;

  prep_kernel<<<512, 256, 0, stream>>>(x, gstat, wq, wk, wv, wp, wB);
  gnqkv_kernel<<<512, 256, 0, stream>>>(x, gstat, gn_scale, gn_bias, wB, bq, bk, bv, qT, kT, vB);
  attn_kernel<<<512, 256, 0, stream>>>(qT, kT, vB, Op, Lv);
  mergeproj_kernel<<<512, 256, 0, stream>>>(Op, Lv, wpB, bp, x, out);
}

// Round 11
// 158.249 us; speedup vs baseline: 1.2496x; 1.0193x over previous
//
#include <hip/hip_runtime.h>
#include <math.h>

#define B_ 4
#define C_ 128
#define N_ 4096
#define NSPLIT 4
#define MT 32     // keys per iteration
#define PLD 40    // Ps row stride (shorts): 32 + 8 pad
#define HLD 136   // h/q/k tile row stride (shorts): 128 + 8 pad
#define VTLD 24   // gnqkv v-tile row stride (shorts): 16 + 8 pad (48 B = 3x16 ✓)

typedef float floatx4 __attribute__((ext_vector_type(4)));
typedef short bf16x8 __attribute__((ext_vector_type(8)));

__device__ __forceinline__ ushort f2bf(float f) {  // RNE
  unsigned u = __float_as_uint(f);
  return (ushort)((u + 0x7FFF + ((u >> 16) & 1)) >> 16);
}
__device__ __forceinline__ float bf2f(ushort u) {
  return __uint_as_float(((unsigned)u) << 16);
}
// pack two floats -> (hi16(a)<<16)|hi16(b), round-half-up
__device__ __forceinline__ unsigned pkbf(float a, float b) {
  return __builtin_amdgcn_perm(__float_as_uint(a) + 0x8000u,
                               __float_as_uint(b) + 0x8000u, 0x07060302u);
}
// async global -> LDS, 16B per lane; LDS dest = uniform base + lane*16
__device__ __forceinline__ void gl2lds16(const ushort* g, ushort* l) {
  __builtin_amdgcn_global_load_lds(
      (const __attribute__((address_space(1))) void*)g,
      (__attribute__((address_space(3))) void*)l, 16, 0, 0);
}

// ---------------- fused: gn_stats (blocks 0..255) + weight cvt (256..511) ----------------
__global__ __launch_bounds__(256) void prep_kernel(
    const float* __restrict__ x, float* __restrict__ gstat,
    const float* __restrict__ wq, const float* __restrict__ wk,
    const float* __restrict__ wv, const float* __restrict__ wp,
    ushort* __restrict__ wB) {
  if (blockIdx.x >= 256) {   // weight convert: 65536 elems
    int i = (blockIdx.x - 256) * 256 + threadIdx.x;
    int m = i >> 14, j = i & 16383;
    const float* src = (m == 0) ? wq : (m == 1) ? wk : (m == 2) ? wv : wp;
    wB[i] = f2bf(src[j]);
    return;
  }
  int b = blockIdx.x >> 6, g = (blockIdx.x >> 3) & 7, part = blockIdx.x & 7;
  const float4* xp = (const float4*)(x + (size_t)(b * C_ + g * 16) * N_) + part * 2048;
  float s = 0.f, ss = 0.f;
  for (int i = threadIdx.x; i < 2048; i += 256) {
    float4 v = xp[i];
    s += v.x + v.y + v.z + v.w;
    ss += v.x * v.x + v.y * v.y + v.z * v.z + v.w * v.w;
  }
  #pragma unroll
  for (int o = 32; o > 0; o >>= 1) {
    s += __shfl_down(s, o, 64);
    ss += __shfl_down(ss, o, 64);
  }
  __shared__ float rs[4], rss[4];
  int wid = threadIdx.x >> 6, lane = threadIdx.x & 63;
  if (lane == 0) { rs[wid] = s; rss[wid] = ss; }
  __syncthreads();
  if (threadIdx.x == 0) {
    int slot = (b * 8 + g) * 8 + part;
    gstat[slot]       = rs[0] + rs[1] + rs[2] + rs[3];
    gstat[256 + slot] = rss[0] + rss[1] + rss[2] + rss[3];
  }
}

// ---------------- fused GN-apply + QKV MFMA: grid 1024 = (b, 16-n tile) ----------------
__global__ __launch_bounds__(256) void gnqkv_kernel(
    const float* __restrict__ x, const float* __restrict__ gstat,
    const float* __restrict__ scale, const float* __restrict__ bias,
    const ushort* __restrict__ wB,
    const float* __restrict__ bq, const float* __restrict__ bk,
    const float* __restrict__ bv,
    ushort* __restrict__ qT, ushort* __restrict__ kT, ushort* __restrict__ vB) {
  __shared__ __align__(16) ushort hs[16][HLD];
  __shared__ __align__(16) ushort Qt[16][HLD];
  __shared__ __align__(16) ushort Kt[16][HLD];
  __shared__ __align__(16) ushort Vt[128][VTLD];
  __shared__ float sSc[C_], sBi[C_];
  int tid = threadIdx.x;
  int b = blockIdx.x >> 8;
  int n0 = (blockIdx.x & 255) * 16;
  if (tid < 128) {
    int g = tid >> 4;
    float S = 0.f, SS = 0.f;
    #pragma unroll
    for (int p = 0; p < 8; ++p) {
      S  += gstat[(b * 8 + g) * 8 + p];
      SS += gstat[256 + (b * 8 + g) * 8 + p];
    }
    float mu = S * (1.f / 65536.f);
    float var = SS * (1.f / 65536.f) - mu * mu;
    float rstd = rsqrtf(var + 1e-6f);
    float sc = scale[tid] * rstd;
    sSc[tid] = sc;
    sBi[tid] = bias[tid] - mu * sc;
  }
  __syncthreads();
  #pragma unroll
  for (int k2 = 0; k2 < 2; ++k2) {   // 128 c x 4 float4 (16 n) = 512
    int i = tid + k2 * 256;
    int c = i >> 2, n4 = i & 3;
    float4 v = *(const float4*)(x + (size_t)(b * C_ + c) * N_ + n0 + n4 * 4);
    float sc = sSc[c], bi = sBi[c];
    hs[n4 * 4 + 0][c] = f2bf(v.x * sc + bi);
    hs[n4 * 4 + 1][c] = f2bf(v.y * sc + bi);
    hs[n4 * 4 + 2][c] = f2bf(v.z * sc + bi);
    hs[n4 * 4 + 3][c] = f2bf(v.w * sc + bi);
  }
  __syncthreads();
  int lane = tid & 63, w = tid >> 6;
  int col = lane & 15, quad = lane >> 4;
  int oh = w * 32;   // each wave: 32 output channels, same 16 n
  bf16x8 hf[4];
  #pragma unroll
  for (int kc = 0; kc < 4; ++kc)
    hf[kc] = *(const bf16x8*)&hs[col][kc * 32 + quad * 8];
  const ushort* Wq = wB;
  const ushort* Wk = wB + 16384;
  const ushort* Wv = wB + 32768;
  const float scl = 0.12751879752224991f;  // 128^-0.5 * log2(e)
  #pragma unroll
  for (int ot = 0; ot < 2; ++ot) {
    int o0 = oh + ot * 16;
    floatx4 aq = (floatx4)0.f, ak = (floatx4)0.f, av = (floatx4)0.f;
    #pragma unroll
    for (int kc = 0; kc < 4; ++kc) {
      int wo = (o0 + col) * C_ + kc * 32 + quad * 8;
      aq = __builtin_amdgcn_mfma_f32_16x16x32_bf16(*(const bf16x8*)&Wq[wo], hf[kc], aq, 0, 0, 0);
      ak = __builtin_amdgcn_mfma_f32_16x16x32_bf16(*(const bf16x8*)&Wk[wo], hf[kc], ak, 0, 0, 0);
      av = __builtin_amdgcn_mfma_f32_16x16x32_bf16(*(const bf16x8*)&Wv[wo], hf[kc], av, 0, 0, 0);
    }
    float4 bqv = *(const float4*)&bq[o0 + quad * 4];
    float4 bkv = *(const float4*)&bk[o0 + quad * 4];
    float4 bvv = *(const float4*)&bv[o0 + quad * 4];
    uint2 qs = { pkbf((aq[1] + bqv.y) * scl, (aq[0] + bqv.x) * scl),
                 pkbf((aq[3] + bqv.w) * scl, (aq[2] + bqv.z) * scl) };
    uint2 ks = { pkbf(ak[1] + bkv.y, ak[0] + bkv.x),
                 pkbf(ak[3] + bkv.w, ak[2] + bkv.z) };
    *(uint2*)&Qt[col][o0 + quad * 4] = qs;
    *(uint2*)&Kt[col][o0 + quad * 4] = ks;
    float vv[4] = {av[0] + bvv.x, av[1] + bvv.y, av[2] + bvv.z, av[3] + bvv.w};
    #pragma unroll
    for (int r = 0; r < 4; ++r)
      Vt[o0 + quad * 4 + r][col] = f2bf(vv[r]);
  }
  __syncthreads();
  // coalesced stores: q/k 16 rows x 16 uint4 = 256; v 128 o x 2 uint4 = 256
  {
    int row = tid >> 4, seg = tid & 15;
    size_t dst = ((size_t)b * N_ + n0 + row) * C_ + seg * 8;
    *(uint4*)(qT + dst) = *(const uint4*)&Qt[row][seg * 8];
    *(uint4*)(kT + dst) = *(const uint4*)&Kt[row][seg * 8];
  }
  {
    int o = tid >> 1, seg = tid & 1;
    *(uint4*)(vB + ((size_t)b * C_ + o) * N_ + n0 + seg * 8) = *(const uint4*)&Vt[o][seg * 8];
  }
}

// ---------------- MFMA flash attention: 64-q blocks, 4 blocks/CU, no-max softmax ----------------
// grid 1024: qblk=bx&63, sp=(bx>>6)&3, b=bx>>8.  256 thr = 4 waves x 16 q-rows
__global__ __launch_bounds__(256, 4) void attn_kernel(
    const ushort* __restrict__ qT, const ushort* __restrict__ kT,
    const ushort* __restrict__ vB, ushort* __restrict__ Op,
    float* __restrict__ Lv) {
  __shared__ __align__(16) ushort Ks[2][MT * 128];   // 2 x 8 KB (chunk-swizzled by row&7)
  __shared__ __align__(16) ushort Vs[2][C_ * MT];    // 2 x 8 KB
  __shared__ __align__(16) ushort Ps[64 * PLD];      // 5 KB
  int qblk = blockIdx.x & 63;
  int sp = (blockIdx.x >> 6) & 3;
  int b = blockIdx.x >> 8;
  int n0 = qblk * 64;
  int tid = threadIdx.x, lane = tid & 63, w = tid >> 6;
  int col = lane & 15, quad = lane >> 4;
  int wu = __builtin_amdgcn_readfirstlane(w);
  const ushort* kTb = kT + (size_t)b * N_ * C_;
  const ushort* vBb = vB + (size_t)b * C_ * N_;

  bf16x8 qf[4];   // Q B-frags for this wave's 16 q-rows (direct from global, L2-hot)
  #pragma unroll
  for (int kc = 0; kc < 4; ++kc)
    qf[kc] = *(const bf16x8*)(qT + ((size_t)b * N_ + n0 + w * 16 + col) * C_ + kc * 32 + quad * 8);

  floatx4 Oacc[8];
  #pragma unroll
  for (int ct = 0; ct < 8; ++ct) Oacc[ct] = (floatx4)0.f;
  float lacc = 0.f;   // per-lane l partial; reduced across quads once at the end

  // K: 32 rows x 256B; LDS pos p of row r holds global chunk p^(r&7).
  // V: 128 rows x 64B; no swizzle.
  #define STAGE(m0v, buf)                                                              \
    {                                                                                  \
      _Pragma("unroll")                                                                \
      for (int j = 0; j < 2; ++j) {                                                    \
        int inst = wu * 2 + j;                                                         \
        int r = inst * 4 + (lane >> 4);                                                \
        int pos = (lane & 15) ^ (r & 7);                                               \
        gl2lds16(kTb + (size_t)((m0v) + r) * 128 + pos * 8, &Ks[buf][inst * 512]);     \
      }                                                                                \
      _Pragma("unroll")                                                                \
      for (int j = 0; j < 2; ++j) {                                                    \
        int inst = wu * 2 + j;                                                         \
        int c = inst * 16 + (lane >> 2);                                               \
        gl2lds16(vBb + (size_t)c * N_ + (m0v) + (lane & 3) * 8, &Vs[buf][inst * 512]); \
      }                                                                                \
    }

  STAGE(sp * 1024, 0);
  __syncthreads();

  for (int it = 0; it < 1024 / MT; ++it) {
    if (it < 1024 / MT - 1) STAGE(sp * 1024 + (it + 1) * MT, (it + 1) & 1);
    const ushort* KsB = Ks[it & 1];
    const ushort* VsB = Vs[it & 1];

    // S^T = K·Q^T per 16-m tile (rows m in-register, cols q)
    floatx4 st[2];
    #pragma unroll
    for (int mt = 0; mt < 2; ++mt) {
      int row = mt * 16 + col;
      bf16x8 kf[4];
      #pragma unroll
      for (int kc = 0; kc < 4; ++kc)
        kf[kc] = *(const bf16x8*)&KsB[row * 128 + (((4 * kc + quad) ^ (col & 7)) * 8)];
      floatx4 acc = (floatx4)0.f;
      #pragma unroll
      for (int kc = 0; kc < 4; ++kc)
        acc = __builtin_amdgcn_mfma_f32_16x16x32_bf16(kf[kc], qf[kc], acc, 0, 0, 0);
      st[mt] = acc;
    }
    // no-max softmax: p = exp2(S) straight off the MFMA; lacc accumulates per-lane.
    int prow = (w * 16 + col) * PLD;
    #pragma unroll
    for (int mt = 0; mt < 2; ++mt) {
      float p0 = exp2f(st[mt][0]);
      float p1 = exp2f(st[mt][1]);
      float p2 = exp2f(st[mt][2]);
      float p3 = exp2f(st[mt][3]);
      uint2 pk = { pkbf(p1, p0), pkbf(p3, p2) };
      *(uint2*)&Ps[prow + mt * 16 + quad * 4] = pk;
      lacc += (p0 + p1) + (p2 + p3);
    }
    // PV: A = P[q][m] (wave-private rows), B = V[c][m]
    bf16x8 pf = *(const bf16x8*)&Ps[prow + quad * 8];
    #pragma unroll
    for (int ct = 0; ct < 8; ++ct) {
      bf16x8 vf = *(const bf16x8*)&VsB[(ct * 16 + col) * MT + quad * 8];
      Oacc[ct] = __builtin_amdgcn_mfma_f32_16x16x32_bf16(pf, vf, Oacc[ct], 0, 0, 0);
    }
    __syncthreads();   // drains prefetch (vmcnt) + gates dbuf reuse
  }

  // epilogue: Op[sp][b][n][c] bf16 (unnormalized) + l
  ushort* OpB = Op + (((size_t)sp * B_ + b) * N_ + n0 + w * 16) * C_;
  #pragma unroll
  for (int ct = 0; ct < 8; ++ct)
    #pragma unroll
    for (int r = 0; r < 4; ++r)
      OpB[(size_t)(quad * 4 + r) * C_ + ct * 16 + col] = f2bf(Oacc[ct][r]);
  float lsum = lacc;
  lsum += __shfl_xor(lsum, 16, 64);
  lsum += __shfl_xor(lsum, 32, 64);
  if (quad == 0) {
    int idx = b * N_ + n0 + w * 16 + col;
    Lv[(size_t)sp * (B_ * N_) + idx] = lsum;
  }
}

// ---------------- fused merge(4 splits, no-max) + proj MFMA + residual ----------------
// grid 1024 = (b, 16-n tile); Op loads coalesced via LDS tile
__global__ __launch_bounds__(256) void mergeproj_kernel(
    const ushort* __restrict__ Op, const float* __restrict__ Lv,
    const ushort* __restrict__ wpB, const float* __restrict__ bp,
    const float* __restrict__ x, float* __restrict__ out) {
  __shared__ __align__(16) ushort tile[16 * HLD];
  int tid = threadIdx.x;
  int b = blockIdx.x >> 8;
  int n0 = (blockIdx.x & 255) * 16;
  {  // stage: thread owns (n = tid>>4, chunk cc = tid&15) -> one uint4, all 128 c covered
    int n = tid >> 4, cc = tid & 15;
    int nIdx = b * N_ + n0 + n;
    float den = Lv[0 * (B_ * N_) + nIdx] + Lv[1 * (B_ * N_) + nIdx] +
                Lv[2 * (B_ * N_) + nIdx] + Lv[3 * (B_ * N_) + nIdx];
    float inv = 1.f / den;
    float o[8];
    #pragma unroll
    for (int j = 0; j < 8; ++j) o[j] = 0.f;
    #pragma unroll
    for (int sp = 0; sp < NSPLIT; ++sp) {
      uint4 d = *(const uint4*)&Op[((size_t)sp * (B_ * N_) + nIdx) * C_ + cc * 8];
      unsigned dd[4] = {d.x, d.y, d.z, d.w};
      #pragma unroll
      for (int j = 0; j < 4; ++j) {
        o[j * 2]     += bf2f((ushort)(dd[j] & 0xFFFF));
        o[j * 2 + 1] += bf2f((ushort)(dd[j] >> 16));
      }
    }
    uint4 res;
    res.x = pkbf(o[1] * inv, o[0] * inv);
    res.y = pkbf(o[3] * inv, o[2] * inv);
    res.z = pkbf(o[5] * inv, o[4] * inv);
    res.w = pkbf(o[7] * inv, o[6] * inv);
    *(uint4*)&tile[n * HLD + cc * 8] = res;
  }
  __syncthreads();
  int lane = tid & 63, w = tid >> 6;
  int col = lane & 15, quad = lane >> 4;
  int oh = w * 32;
  bf16x8 hf[4];
  #pragma unroll
  for (int kc = 0; kc < 4; ++kc)
    hf[kc] = *(const bf16x8*)&tile[col * HLD + kc * 32 + quad * 8];
  #pragma unroll
  for (int ot = 0; ot < 2; ++ot) {
    int o0 = oh + ot * 16;
    floatx4 acc = (floatx4)0.f;
    #pragma unroll
    for (int kc = 0; kc < 4; ++kc) {
      int wo = (o0 + col) * C_ + kc * 32 + quad * 8;
      acc = __builtin_amdgcn_mfma_f32_16x16x32_bf16(*(const bf16x8*)&wpB[wo], hf[kc], acc, 0, 0, 0);
    }
    float4 bpv = *(const float4*)&bp[o0 + quad * 4];
    float bb[4] = {bpv.x, bpv.y, bpv.z, bpv.w};
    #pragma unroll
    for (int r = 0; r < 4; ++r) {
      size_t idx = ((size_t)b * C_ + o0 + quad * 4 + r) * N_ + n0 + col;
      out[idx] = acc[r] + bb[r] + x[idx];
    }
  }
}

extern "C" void kernel_launch(void* const* d_in, const int* in_sizes, int n_in,
                              void* d_out, int out_size, void* d_ws, size_t ws_size,
                              hipStream_t stream) {
  const float* x        = (const float*)d_in[0];
  const float* gn_scale = (const float*)d_in[1];
  const float* gn_bias  = (const float*)d_in[2];
  const float* wq = (const float*)d_in[3];
  const float* bq = (const float*)d_in[4];
  const float* wk = (const float*)d_in[5];
  const float* bk = (const float*)d_in[6];
  const float* wv = (const float*)d_in[7];
  const float* bv = (const float*)d_in[8];
  const float* wp = (const float*)d_in[9];
  const float* bp = (const float*)d_in[10];
  float* out = (float*)d_out;

  // workspace map (32 MB):
  // [256K,512K) Lv | [512K,640K) wB (4x32KB bf16) | [640K,+2KB) gstat
  // [4M,8M) qT | [8M,12M) kT | [12M,16M) vB | [16M,32M) Op[4][B][N][C] bf16
  char* ws = (char*)d_ws;
  float*  Lv    = (float*)(ws + 262144);
  ushort* wB    = (ushort*)(ws + 524288);
  float*  gstat = (float*)(ws + 655360);
  ushort* qT    = (ushort*)(ws + (4u << 20));
  ushort* kT    = (ushort*)(ws + (8u << 20));
  ushort* vB    = (ushort*)(ws + (12u << 20));
  ushort* Op    = (ushort*)(ws + (16u << 20));
  ushort* wpB   = wB + 49152;

  prep_kernel<<<512, 256, 0, stream>>>(x, gstat, wq, wk, wv, wp, wB);
  gnqkv_kernel<<<1024, 256, 0, stream>>>(x, gstat, gn_scale, gn_bias, wB, bq, bk, bv, qT, kT, vB);
  attn_kernel<<<1024, 256, 0, stream>>>(qT, kT, vB, Op, Lv);
  mergeproj_kernel<<<1024, 256, 0, stream>>>(Op, Lv, wpB, bp, x, out);
}

// Round 12
// 154.832 us; speedup vs baseline: 1.2772x; 1.0221x over previous
//
#include <hip/hip_runtime.h>
#include <math.h>

#define B_ 4
#define C_ 128
#define N_ 4096
#define NSPLIT 4
#define MT 32     // keys per iteration
#define PLD 40    // Ps row stride (shorts): 32 + 8 pad
#define HLD 136   // h/q/k tile row stride (shorts): 128 + 8 pad
#define VTLD 24   // gnqkv v-tile row stride (shorts): 16 + 8 pad (48 B = 3x16 ✓)

typedef float floatx4 __attribute__((ext_vector_type(4)));
typedef short bf16x8 __attribute__((ext_vector_type(8)));

__device__ __forceinline__ ushort f2bf(float f) {  // RNE
  unsigned u = __float_as_uint(f);
  return (ushort)((u + 0x7FFF + ((u >> 16) & 1)) >> 16);
}
__device__ __forceinline__ float bf2f(ushort u) {
  return __uint_as_float(((unsigned)u) << 16);
}
// pack two floats -> (hi16(a)<<16)|hi16(b), round-half-up
__device__ __forceinline__ unsigned pkbf(float a, float b) {
  return __builtin_amdgcn_perm(__float_as_uint(a) + 0x8000u,
                               __float_as_uint(b) + 0x8000u, 0x07060302u);
}
// async global -> LDS, 16B per lane; LDS dest = uniform base + lane*16
__device__ __forceinline__ void gl2lds16(const ushort* g, ushort* l) {
  __builtin_amdgcn_global_load_lds(
      (const __attribute__((address_space(1))) void*)g,
      (__attribute__((address_space(3))) void*)l, 16, 0, 0);
}

// ---------------- fused: gn_stats (blocks 0..255) + weight cvt (256..511) ----------------
__global__ __launch_bounds__(256) void prep_kernel(
    const float* __restrict__ x, float* __restrict__ gstat,
    const float* __restrict__ wq, const float* __restrict__ wk,
    const float* __restrict__ wv, const float* __restrict__ wp,
    ushort* __restrict__ wB) {
  if (blockIdx.x >= 256) {   // weight convert: 65536 elems
    int i = (blockIdx.x - 256) * 256 + threadIdx.x;
    int m = i >> 14, j = i & 16383;
    const float* src = (m == 0) ? wq : (m == 1) ? wk : (m == 2) ? wv : wp;
    wB[i] = f2bf(src[j]);
    return;
  }
  int b = blockIdx.x >> 6, g = (blockIdx.x >> 3) & 7, part = blockIdx.x & 7;
  const float4* xp = (const float4*)(x + (size_t)(b * C_ + g * 16) * N_) + part * 2048;
  float s = 0.f, ss = 0.f;
  for (int i = threadIdx.x; i < 2048; i += 256) {
    float4 v = xp[i];
    s += v.x + v.y + v.z + v.w;
    ss += v.x * v.x + v.y * v.y + v.z * v.z + v.w * v.w;
  }
  #pragma unroll
  for (int o = 32; o > 0; o >>= 1) {
    s += __shfl_down(s, o, 64);
    ss += __shfl_down(ss, o, 64);
  }
  __shared__ float rs[4], rss[4];
  int wid = threadIdx.x >> 6, lane = threadIdx.x & 63;
  if (lane == 0) { rs[wid] = s; rss[wid] = ss; }
  __syncthreads();
  if (threadIdx.x == 0) {
    int slot = (b * 8 + g) * 8 + part;
    gstat[slot]       = rs[0] + rs[1] + rs[2] + rs[3];
    gstat[256 + slot] = rss[0] + rss[1] + rss[2] + rss[3];
  }
}

// ---------------- fused GN-apply + QKV MFMA: grid 1024 = (b, 16-n tile) ----------------
__global__ __launch_bounds__(256) void gnqkv_kernel(
    const float* __restrict__ x, const float* __restrict__ gstat,
    const float* __restrict__ scale, const float* __restrict__ bias,
    const ushort* __restrict__ wB,
    const float* __restrict__ bq, const float* __restrict__ bk,
    const float* __restrict__ bv,
    ushort* __restrict__ qT, ushort* __restrict__ kT, ushort* __restrict__ vB) {
  __shared__ __align__(16) ushort hs[16][HLD];
  __shared__ __align__(16) ushort Qt[16][HLD];
  __shared__ __align__(16) ushort Kt[16][HLD];
  __shared__ __align__(16) ushort Vt[128][VTLD];
  __shared__ float sSc[C_], sBi[C_];
  int tid = threadIdx.x;
  int b = blockIdx.x >> 8;
  int n0 = (blockIdx.x & 255) * 16;
  if (tid < 128) {
    int g = tid >> 4;
    float S = 0.f, SS = 0.f;
    #pragma unroll
    for (int p = 0; p < 8; ++p) {
      S  += gstat[(b * 8 + g) * 8 + p];
      SS += gstat[256 + (b * 8 + g) * 8 + p];
    }
    float mu = S * (1.f / 65536.f);
    float var = SS * (1.f / 65536.f) - mu * mu;
    float rstd = rsqrtf(var + 1e-6f);
    float sc = scale[tid] * rstd;
    sSc[tid] = sc;
    sBi[tid] = bias[tid] - mu * sc;
  }
  __syncthreads();
  #pragma unroll
  for (int k2 = 0; k2 < 2; ++k2) {   // 128 c x 4 float4 (16 n) = 512
    int i = tid + k2 * 256;
    int c = i >> 2, n4 = i & 3;
    float4 v = *(const float4*)(x + (size_t)(b * C_ + c) * N_ + n0 + n4 * 4);
    float sc = sSc[c], bi = sBi[c];
    hs[n4 * 4 + 0][c] = f2bf(v.x * sc + bi);
    hs[n4 * 4 + 1][c] = f2bf(v.y * sc + bi);
    hs[n4 * 4 + 2][c] = f2bf(v.z * sc + bi);
    hs[n4 * 4 + 3][c] = f2bf(v.w * sc + bi);
  }
  __syncthreads();
  int lane = tid & 63, w = tid >> 6;
  int col = lane & 15, quad = lane >> 4;
  int oh = w * 32;   // each wave: 32 output channels, same 16 n
  bf16x8 hf[4];
  #pragma unroll
  for (int kc = 0; kc < 4; ++kc)
    hf[kc] = *(const bf16x8*)&hs[col][kc * 32 + quad * 8];
  const ushort* Wq = wB;
  const ushort* Wk = wB + 16384;
  const ushort* Wv = wB + 32768;
  const float scl = 0.12751879752224991f;  // 128^-0.5 * log2(e)
  #pragma unroll
  for (int ot = 0; ot < 2; ++ot) {
    int o0 = oh + ot * 16;
    floatx4 aq = (floatx4)0.f, ak = (floatx4)0.f, av = (floatx4)0.f;
    #pragma unroll
    for (int kc = 0; kc < 4; ++kc) {
      int wo = (o0 + col) * C_ + kc * 32 + quad * 8;
      aq = __builtin_amdgcn_mfma_f32_16x16x32_bf16(*(const bf16x8*)&Wq[wo], hf[kc], aq, 0, 0, 0);
      ak = __builtin_amdgcn_mfma_f32_16x16x32_bf16(*(const bf16x8*)&Wk[wo], hf[kc], ak, 0, 0, 0);
      av = __builtin_amdgcn_mfma_f32_16x16x32_bf16(*(const bf16x8*)&Wv[wo], hf[kc], av, 0, 0, 0);
    }
    float4 bqv = *(const float4*)&bq[o0 + quad * 4];
    float4 bkv = *(const float4*)&bk[o0 + quad * 4];
    float4 bvv = *(const float4*)&bv[o0 + quad * 4];
    uint2 qs = { pkbf((aq[1] + bqv.y) * scl, (aq[0] + bqv.x) * scl),
                 pkbf((aq[3] + bqv.w) * scl, (aq[2] + bqv.z) * scl) };
    uint2 ks = { pkbf(ak[1] + bkv.y, ak[0] + bkv.x),
                 pkbf(ak[3] + bkv.w, ak[2] + bkv.z) };
    *(uint2*)&Qt[col][o0 + quad * 4] = qs;
    *(uint2*)&Kt[col][o0 + quad * 4] = ks;
    float vv[4] = {av[0] + bvv.x, av[1] + bvv.y, av[2] + bvv.z, av[3] + bvv.w};
    #pragma unroll
    for (int r = 0; r < 4; ++r)
      Vt[o0 + quad * 4 + r][col] = f2bf(vv[r]);
  }
  __syncthreads();
  {
    int row = tid >> 4, seg = tid & 15;
    size_t dst = ((size_t)b * N_ + n0 + row) * C_ + seg * 8;
    *(uint4*)(qT + dst) = *(const uint4*)&Qt[row][seg * 8];
    *(uint4*)(kT + dst) = *(const uint4*)&Kt[row][seg * 8];
  }
  {
    int o = tid >> 1, seg = tid & 1;
    *(uint4*)(vB + ((size_t)b * C_ + o) * N_ + n0 + seg * 8) = *(const uint4*)&Vt[o][seg * 8];
  }
}

// ---------------- MFMA flash attention: ct-split PV (low LDS traffic), no-max softmax ----
// grid 512: qblk=bx&31 (128-q tiles), sp=(bx>>5)&3, b=bx>>7.  256 thr = 4 waves
// S-phase: wave w computes S^T for q in [w*32, w*32+32).
// PV-phase: wave w computes O for ALL 128 q, channels [w*32, (w+1)*32).
__global__ __launch_bounds__(256, 3) void attn_kernel(
    const ushort* __restrict__ qT, const ushort* __restrict__ kT,
    const ushort* __restrict__ vB, ushort* __restrict__ Op,
    float* __restrict__ Lv) {
  __shared__ __align__(16) ushort Ks[2][MT * 128];   // 2 x 8 KB (chunk-swizzled by row&7)
  __shared__ __align__(16) ushort Vs[2][C_ * MT];    // 2 x 8 KB
  __shared__ __align__(16) ushort Ps[128 * PLD];     // 10 KB, shared across waves
  int qblk = blockIdx.x & 31;
  int sp = (blockIdx.x >> 5) & 3;
  int b = blockIdx.x >> 7;
  int n0 = qblk * 128;
  int tid = threadIdx.x, lane = tid & 63, w = tid >> 6;
  int col = lane & 15, quad = lane >> 4;
  int wu = __builtin_amdgcn_readfirstlane(w);
  const ushort* kTb = kT + (size_t)b * N_ * C_;
  const ushort* vBb = vB + (size_t)b * C_ * N_;

  bf16x8 qf[2][4];   // Q B-frags for this wave's 32 S-rows
  #pragma unroll
  for (int qt = 0; qt < 2; ++qt)
    #pragma unroll
    for (int kc = 0; kc < 4; ++kc)
      qf[qt][kc] = *(const bf16x8*)(qT + ((size_t)b * N_ + n0 + w * 32 + qt * 16 + col) * C_ + kc * 32 + quad * 8);

  floatx4 Oacc[8][2];   // [qt over 128 q][ct over wave's 32 c]
  #pragma unroll
  for (int qt = 0; qt < 8; ++qt)
    #pragma unroll
    for (int ct = 0; ct < 2; ++ct) Oacc[qt][ct] = (floatx4)0.f;
  float lacc[2] = {0.f, 0.f};   // per-lane l partials, one per S q-tile

  #define STAGE(m0v, buf)                                                              \
    {                                                                                  \
      _Pragma("unroll")                                                                \
      for (int j = 0; j < 2; ++j) {                                                    \
        int inst = wu * 2 + j;                                                         \
        int r = inst * 4 + (lane >> 4);                                                \
        int pos = (lane & 15) ^ (r & 7);                                               \
        gl2lds16(kTb + (size_t)((m0v) + r) * 128 + pos * 8, &Ks[buf][inst * 512]);     \
      }                                                                                \
      _Pragma("unroll")                                                                \
      for (int j = 0; j < 2; ++j) {                                                    \
        int inst = wu * 2 + j;                                                         \
        int c = inst * 16 + (lane >> 2);                                               \
        gl2lds16(vBb + (size_t)c * N_ + (m0v) + (lane & 3) * 8, &Vs[buf][inst * 512]); \
      }                                                                                \
    }

  STAGE(sp * 1024, 0);
  __syncthreads();

  for (int it = 0; it < 1024 / MT; ++it) {
    if (it < 1024 / MT - 1) STAGE(sp * 1024 + (it + 1) * MT, (it + 1) & 1);
    const ushort* KsB = Ks[it & 1];
    const ushort* VsB = Vs[it & 1];

    // S^T = K·Q^T per 16-m tile (rows m in-register, cols q = wave's 32)
    floatx4 st[2][2];
    #pragma unroll
    for (int mt = 0; mt < 2; ++mt) {
      int row = mt * 16 + col;
      bf16x8 kf[4];
      #pragma unroll
      for (int kc = 0; kc < 4; ++kc)
        kf[kc] = *(const bf16x8*)&KsB[row * 128 + (((4 * kc + quad) ^ (col & 7)) * 8)];
      #pragma unroll
      for (int qt = 0; qt < 2; ++qt) {
        floatx4 acc = (floatx4)0.f;
        #pragma unroll
        for (int kc = 0; kc < 4; ++kc)
          acc = __builtin_amdgcn_mfma_f32_16x16x32_bf16(kf[kc], qf[qt][kc], acc, 0, 0, 0);
        st[qt][mt] = acc;
      }
    }
    // no-max softmax: p = exp2(S); per-lane per-qt lacc (summed over this lane's m values)
    #pragma unroll
    for (int qt = 0; qt < 2; ++qt) {
      int prow = (w * 32 + qt * 16 + col) * PLD;
      #pragma unroll
      for (int mt = 0; mt < 2; ++mt) {
        float p0 = exp2f(st[qt][mt][0]);
        float p1 = exp2f(st[qt][mt][1]);
        float p2 = exp2f(st[qt][mt][2]);
        float p3 = exp2f(st[qt][mt][3]);
        uint2 pk = { pkbf(p1, p0), pkbf(p3, p2) };
        *(uint2*)&Ps[prow + mt * 16 + quad * 4] = pk;
        lacc[qt] += (p0 + p1) + (p2 + p3);
      }
    }
    __syncthreads();   // Ps visible to all waves (also drains staging vmcnt)
    // PV: wave w owns channels [w*32, w*32+32), all 128 q.
    #pragma unroll
    for (int ct = 0; ct < 2; ++ct) {
      bf16x8 vf = *(const bf16x8*)&VsB[(w * 32 + ct * 16 + col) * MT + quad * 8];
      #pragma unroll
      for (int qt = 0; qt < 8; ++qt) {
        bf16x8 pf = *(const bf16x8*)&Ps[(qt * 16 + col) * PLD + quad * 8];
        Oacc[qt][ct] = __builtin_amdgcn_mfma_f32_16x16x32_bf16(pf, vf, Oacc[qt][ct], 0, 0, 0);
      }
    }
    __syncthreads();   // all waves done with Ps + Ks/Vs[cur] before overwrite
  }

  // epilogue: Op[sp][b][n][c] bf16 (unnormalized)
  ushort* OpB = Op + (((size_t)sp * B_ + b) * N_ + n0) * C_;
  #pragma unroll
  for (int qt = 0; qt < 8; ++qt)
    #pragma unroll
    for (int ct = 0; ct < 2; ++ct)
      #pragma unroll
      for (int r = 0; r < 4; ++r)
        OpB[(size_t)(qt * 16 + quad * 4 + r) * C_ + w * 32 + ct * 16 + col] = f2bf(Oacc[qt][ct][r]);
  // l for this wave's S-rows: lane holds partial over its 8 m-values; sum across the
  // 4 lane-groups (lanes with same col) via shfl over 16/32.
  #pragma unroll
  for (int qt = 0; qt < 2; ++qt) {
    float lsum = lacc[qt];
    lsum += __shfl_xor(lsum, 16, 64);
    lsum += __shfl_xor(lsum, 32, 64);
    if (quad == 0) {
      int idx = b * N_ + n0 + w * 32 + qt * 16 + col;
      Lv[(size_t)sp * (B_ * N_) + idx] = lsum;
    }
  }
}

// ---------------- fused merge(4 splits, no-max) + proj MFMA + residual ----------------
// grid 1024 = (b, 16-n tile); Op loads coalesced via LDS tile
__global__ __launch_bounds__(256) void mergeproj_kernel(
    const ushort* __restrict__ Op, const float* __restrict__ Lv,
    const ushort* __restrict__ wpB, const float* __restrict__ bp,
    const float* __restrict__ x, float* __restrict__ out) {
  __shared__ __align__(16) ushort tile[16 * HLD];
  int tid = threadIdx.x;
  int b = blockIdx.x >> 8;
  int n0 = (blockIdx.x & 255) * 16;
  {
    int n = tid >> 4, cc = tid & 15;
    int nIdx = b * N_ + n0 + n;
    float den = Lv[0 * (B_ * N_) + nIdx] + Lv[1 * (B_ * N_) + nIdx] +
                Lv[2 * (B_ * N_) + nIdx] + Lv[3 * (B_ * N_) + nIdx];
    float inv = 1.f / den;
    float o[8];
    #pragma unroll
    for (int j = 0; j < 8; ++j) o[j] = 0.f;
    #pragma unroll
    for (int sp = 0; sp < NSPLIT; ++sp) {
      uint4 d = *(const uint4*)&Op[((size_t)sp * (B_ * N_) + nIdx) * C_ + cc * 8];
      unsigned dd[4] = {d.x, d.y, d.z, d.w};
      #pragma unroll
      for (int j = 0; j < 4; ++j) {
        o[j * 2]     += bf2f((ushort)(dd[j] & 0xFFFF));
        o[j * 2 + 1] += bf2f((ushort)(dd[j] >> 16));
      }
    }
    uint4 res;
    res.x = pkbf(o[1] * inv, o[0] * inv);
    res.y = pkbf(o[3] * inv, o[2] * inv);
    res.z = pkbf(o[5] * inv, o[4] * inv);
    res.w = pkbf(o[7] * inv, o[6] * inv);
    *(uint4*)&tile[n * HLD + cc * 8] = res;
  }
  __syncthreads();
  int lane = tid & 63, w = tid >> 6;
  int col = lane & 15, quad = lane >> 4;
  int oh = w * 32;
  bf16x8 hf[4];
  #pragma unroll
  for (int kc = 0; kc < 4; ++kc)
    hf[kc] = *(const bf16x8*)&tile[col * HLD + kc * 32 + quad * 8];
  #pragma unroll
  for (int ot = 0; ot < 2; ++ot) {
    int o0 = oh + ot * 16;
    floatx4 acc = (floatx4)0.f;
    #pragma unroll
    for (int kc = 0; kc < 4; ++kc) {
      int wo = (o0 + col) * C_ + kc * 32 + quad * 8;
      acc = __builtin_amdgcn_mfma_f32_16x16x32_bf16(*(const bf16x8*)&wpB[wo], hf[kc], acc, 0, 0, 0);
    }
    float4 bpv = *(const float4*)&bp[o0 + quad * 4];
    float bb[4] = {bpv.x, bpv.y, bpv.z, bpv.w};
    #pragma unroll
    for (int r = 0; r < 4; ++r) {
      size_t idx = ((size_t)b * C_ + o0 + quad * 4 + r) * N_ + n0 + col;
      out[idx] = acc[r] + bb[r] + x[idx];
    }
  }
}

extern "C" void kernel_launch(void* const* d_in, const int* in_sizes, int n_in,
                              void* d_out, int out_size, void* d_ws, size_t ws_size,
                              hipStream_t stream) {
  const float* x        = (const float*)d_in[0];
  const float* gn_scale = (const float*)d_in[1];
  const float* gn_bias  = (const float*)d_in[2];
  const float* wq = (const float*)d_in[3];
  const float* bq = (const float*)d_in[4];
  const float* wk = (const float*)d_in[5];
  const float* bk = (const float*)d_in[6];
  const float* wv = (const float*)d_in[7];
  const float* bv = (const float*)d_in[8];
  const float* wp = (const float*)d_in[9];
  const float* bp = (const float*)d_in[10];
  float* out = (float*)d_out;

  char* ws = (char*)d_ws;
  float*  Lv    = (float*)(ws + 262144);
  ushort* wB    = (ushort*)(ws + 524288);
  float*  gstat = (float*)(ws + 655360);
  ushort* qT    = (ushort*)(ws + (4u << 20));
  ushort* kT    = (ushort*)(ws + (8u << 20));
  ushort* vB    = (ushort*)(ws + (12u << 20));
  ushort* Op    = (ushort*)(ws + (16u << 20));
  ushort* wpB   = wB + 49152;

  prep_kernel<<<512, 256, 0, stream>>>(x, gstat, wq, wk, wv, wp, wB);
  gnqkv_kernel<<<1024, 256, 0, stream>>>(x, gstat, gn_scale, gn_bias, wB, bq, bk, bv, qT, kT, vB);
  attn_kernel<<<512, 256, 0, stream>>>(qT, kT, vB, Op, Lv);
  mergeproj_kernel<<<1024, 256, 0, stream>>>(Op, Lv, wpB, bp, x, out);
}

// Round 13
// 153.841 us; speedup vs baseline: 1.2854x; 1.0064x over previous
//
#include <hip/hip_runtime.h>
#include <math.h>

#define B_ 4
#define C_ 128
#define N_ 4096
#define NSPLIT 4
#define MT 32     // keys per iteration
#define PLD 40    // Ps row stride (shorts): 32 + 8 pad (80 B, 16B-divisible)
#define HLD 136   // h/q/k tile row stride (shorts): 128 + 8 pad
#define VTLD 24   // gnqkv v-tile row stride (shorts): 16 + 8 pad (48 B = 3x16)

typedef float floatx4 __attribute__((ext_vector_type(4)));
typedef short bf16x8 __attribute__((ext_vector_type(8)));

__device__ __forceinline__ ushort f2bf(float f) {  // RNE
  unsigned u = __float_as_uint(f);
  return (ushort)((u + 0x7FFF + ((u >> 16) & 1)) >> 16);
}
__device__ __forceinline__ float bf2f(ushort u) {
  return __uint_as_float(((unsigned)u) << 16);
}
// pack two floats -> (hi16(a)<<16)|hi16(b), round-half-up
__device__ __forceinline__ unsigned pkbf(float a, float b) {
  return __builtin_amdgcn_perm(__float_as_uint(a) + 0x8000u,
                               __float_as_uint(b) + 0x8000u, 0x07060302u);
}
// async global -> LDS, 16B per lane; LDS dest = uniform base + lane*16
__device__ __forceinline__ void gl2lds16(const ushort* g, ushort* l) {
  __builtin_amdgcn_global_load_lds(
      (const __attribute__((address_space(1))) void*)g,
      (__attribute__((address_space(3))) void*)l, 16, 0, 0);
}

// ---------------- fused: gn_stats (blocks 0..255) + weight cvt (256..511) ----------------
__global__ __launch_bounds__(256) void prep_kernel(
    const float* __restrict__ x, float* __restrict__ gstat,
    const float* __restrict__ wq, const float* __restrict__ wk,
    const float* __restrict__ wv, const float* __restrict__ wp,
    ushort* __restrict__ wB) {
  if (blockIdx.x >= 256) {   // weight convert: 65536 elems
    int i = (blockIdx.x - 256) * 256 + threadIdx.x;
    int m = i >> 14, j = i & 16383;
    const float* src = (m == 0) ? wq : (m == 1) ? wk : (m == 2) ? wv : wp;
    wB[i] = f2bf(src[j]);
    return;
  }
  int b = blockIdx.x >> 6, g = (blockIdx.x >> 3) & 7, part = blockIdx.x & 7;
  const float4* xp = (const float4*)(x + (size_t)(b * C_ + g * 16) * N_) + part * 2048;
  float s = 0.f, ss = 0.f;
  for (int i = threadIdx.x; i < 2048; i += 256) {
    float4 v = xp[i];
    s += v.x + v.y + v.z + v.w;
    ss += v.x * v.x + v.y * v.y + v.z * v.z + v.w * v.w;
  }
  #pragma unroll
  for (int o = 32; o > 0; o >>= 1) {
    s += __shfl_down(s, o, 64);
    ss += __shfl_down(ss, o, 64);
  }
  __shared__ float rs[4], rss[4];
  int wid = threadIdx.x >> 6, lane = threadIdx.x & 63;
  if (lane == 0) { rs[wid] = s; rss[wid] = ss; }
  __syncthreads();
  if (threadIdx.x == 0) {
    int slot = (b * 8 + g) * 8 + part;
    gstat[slot]       = rs[0] + rs[1] + rs[2] + rs[3];
    gstat[256 + slot] = rss[0] + rss[1] + rss[2] + rss[3];
  }
}

// ---------------- fused GN-apply + QKV MFMA: grid 1024 = (b, 16-n tile) ----------------
__global__ __launch_bounds__(256) void gnqkv_kernel(
    const float* __restrict__ x, const float* __restrict__ gstat,
    const float* __restrict__ scale, const float* __restrict__ bias,
    const ushort* __restrict__ wB,
    const float* __restrict__ bq, const float* __restrict__ bk,
    const float* __restrict__ bv,
    ushort* __restrict__ qT, ushort* __restrict__ kT, ushort* __restrict__ vB) {
  __shared__ __align__(16) ushort hs[16][HLD];
  __shared__ __align__(16) ushort Qt[16][HLD];
  __shared__ __align__(16) ushort Kt[16][HLD];
  __shared__ __align__(16) ushort Vt[128][VTLD];
  __shared__ float sSc[C_], sBi[C_];
  int tid = threadIdx.x;
  int b = blockIdx.x >> 8;
  int n0 = (blockIdx.x & 255) * 16;
  if (tid < 128) {
    int g = tid >> 4;
    float S = 0.f, SS = 0.f;
    #pragma unroll
    for (int p = 0; p < 8; ++p) {
      S  += gstat[(b * 8 + g) * 8 + p];
      SS += gstat[256 + (b * 8 + g) * 8 + p];
    }
    float mu = S * (1.f / 65536.f);
    float var = SS * (1.f / 65536.f) - mu * mu;
    float rstd = rsqrtf(var + 1e-6f);
    float sc = scale[tid] * rstd;
    sSc[tid] = sc;
    sBi[tid] = bias[tid] - mu * sc;
  }
  __syncthreads();
  #pragma unroll
  for (int k2 = 0; k2 < 2; ++k2) {   // 128 c x 4 float4 (16 n) = 512
    int i = tid + k2 * 256;
    int c = i >> 2, n4 = i & 3;
    float4 v = *(const float4*)(x + (size_t)(b * C_ + c) * N_ + n0 + n4 * 4);
    float sc = sSc[c], bi = sBi[c];
    hs[n4 * 4 + 0][c] = f2bf(v.x * sc + bi);
    hs[n4 * 4 + 1][c] = f2bf(v.y * sc + bi);
    hs[n4 * 4 + 2][c] = f2bf(v.z * sc + bi);
    hs[n4 * 4 + 3][c] = f2bf(v.w * sc + bi);
  }
  __syncthreads();
  int lane = tid & 63, w = tid >> 6;
  int col = lane & 15, quad = lane >> 4;
  int oh = w * 32;   // each wave: 32 output channels, same 16 n
  bf16x8 hf[4];
  #pragma unroll
  for (int kc = 0; kc < 4; ++kc)
    hf[kc] = *(const bf16x8*)&hs[col][kc * 32 + quad * 8];
  const ushort* Wq = wB;
  const ushort* Wk = wB + 16384;
  const ushort* Wv = wB + 32768;
  const float scl = 0.12751879752224991f;  // 128^-0.5 * log2(e)
  #pragma unroll
  for (int ot = 0; ot < 2; ++ot) {
    int o0 = oh + ot * 16;
    floatx4 aq = (floatx4)0.f, ak = (floatx4)0.f, av = (floatx4)0.f;
    #pragma unroll
    for (int kc = 0; kc < 4; ++kc) {
      int wo = (o0 + col) * C_ + kc * 32 + quad * 8;
      aq = __builtin_amdgcn_mfma_f32_16x16x32_bf16(*(const bf16x8*)&Wq[wo], hf[kc], aq, 0, 0, 0);
      ak = __builtin_amdgcn_mfma_f32_16x16x32_bf16(*(const bf16x8*)&Wk[wo], hf[kc], ak, 0, 0, 0);
      av = __builtin_amdgcn_mfma_f32_16x16x32_bf16(*(const bf16x8*)&Wv[wo], hf[kc], av, 0, 0, 0);
    }
    float4 bqv = *(const float4*)&bq[o0 + quad * 4];
    float4 bkv = *(const float4*)&bk[o0 + quad * 4];
    float4 bvv = *(const float4*)&bv[o0 + quad * 4];
    uint2 qs = { pkbf((aq[1] + bqv.y) * scl, (aq[0] + bqv.x) * scl),
                 pkbf((aq[3] + bqv.w) * scl, (aq[2] + bqv.z) * scl) };
    uint2 ks = { pkbf(ak[1] + bkv.y, ak[0] + bkv.x),
                 pkbf(ak[3] + bkv.w, ak[2] + bkv.z) };
    *(uint2*)&Qt[col][o0 + quad * 4] = qs;
    *(uint2*)&Kt[col][o0 + quad * 4] = ks;
    float vv[4] = {av[0] + bvv.x, av[1] + bvv.y, av[2] + bvv.z, av[3] + bvv.w};
    #pragma unroll
    for (int r = 0; r < 4; ++r)
      Vt[o0 + quad * 4 + r][col] = f2bf(vv[r]);
  }
  __syncthreads();
  {
    int row = tid >> 4, seg = tid & 15;
    size_t dst = ((size_t)b * N_ + n0 + row) * C_ + seg * 8;
    *(uint4*)(qT + dst) = *(const uint4*)&Qt[row][seg * 8];
    *(uint4*)(kT + dst) = *(const uint4*)&Kt[row][seg * 8];
  }
  {
    int o = tid >> 1, seg = tid & 1;
    *(uint4*)(vB + ((size_t)b * C_ + o) * N_ + n0 + seg * 8) = *(const uint4*)&Vt[o][seg * 8];
  }
}

// ---------------- MFMA flash attention: 8-wave blocks, split-m S + split-qc PV ----------
// grid 512: sp=bx&3 (fastest, L2-friendly), qblk=(bx>>2)&31, b=bx>>7.  512 thr = 8 waves.
// S-phase:  wave w -> m-half mtw=w&1 (16 keys), q-group qg=w>>1 (32 q).
// PV-phase: wave w -> q-half qh=w&1 (64 q), channel-quarter cq=w>>1 (32 c).
__global__ __launch_bounds__(512, 4) void attn_kernel(
    const ushort* __restrict__ qT, const ushort* __restrict__ kT,
    const ushort* __restrict__ vB, ushort* __restrict__ Op,
    float* __restrict__ Lv) {
  __shared__ __align__(16) ushort Ks[2][MT * 128];   // 2 x 8 KB (chunk-swizzled by row&7)
  __shared__ __align__(16) ushort Vs[2][C_ * MT];    // 2 x 8 KB
  __shared__ __align__(16) ushort Ps[128 * PLD];     // 10 KB, shared across waves
  __shared__ float lpart[8][2][16];                  // 1 KB
  int sp = blockIdx.x & 3;
  int qblk = (blockIdx.x >> 2) & 31;
  int b = blockIdx.x >> 7;
  int n0 = qblk * 128;
  int tid = threadIdx.x, lane = tid & 63, w = tid >> 6;
  int col = lane & 15, quad = lane >> 4;
  int wu = __builtin_amdgcn_readfirstlane(w);
  int mtw = w & 1, qg = w >> 1;   // S-phase roles
  int qh = w & 1, cq = w >> 1;    // PV-phase roles
  const ushort* kTb = kT + (size_t)b * N_ * C_;
  const ushort* vBb = vB + (size_t)b * C_ * N_;

  bf16x8 qf[2][4];   // Q B-frags for this wave's 32 S-rows (q-group qg)
  #pragma unroll
  for (int qt = 0; qt < 2; ++qt)
    #pragma unroll
    for (int kc = 0; kc < 4; ++kc)
      qf[qt][kc] = *(const bf16x8*)(qT + ((size_t)b * N_ + n0 + qg * 32 + qt * 16 + col) * C_ + kc * 32 + quad * 8);

  floatx4 Oacc[4][2];   // [qt over q-half 64][ct over 32 c]
  #pragma unroll
  for (int qt = 0; qt < 4; ++qt)
    #pragma unroll
    for (int ct = 0; ct < 2; ++ct) Oacc[qt][ct] = (floatx4)0.f;
  float lacc[2] = {0.f, 0.f};   // per-lane l partials for S q-tiles (m-half mtw only)

  // one K inst + one V inst per wave (8 waves cover 32 K rows / 128 V rows)
  #define STAGE(m0v, buf)                                                            \
    {                                                                                \
      int r = wu * 4 + (lane >> 4);                                                  \
      int pos = (lane & 15) ^ (r & 7);                                               \
      gl2lds16(kTb + (size_t)((m0v) + r) * 128 + pos * 8, &Ks[buf][wu * 512]);       \
      int c = wu * 16 + (lane >> 2);                                                 \
      gl2lds16(vBb + (size_t)c * N_ + (m0v) + (lane & 3) * 8, &Vs[buf][wu * 512]);   \
    }

  STAGE(sp * 1024, 0);
  __syncthreads();

  for (int it = 0; it < 1024 / MT; ++it) {
    if (it < 1024 / MT - 1) STAGE(sp * 1024 + (it + 1) * MT, (it + 1) & 1);
    const ushort* KsB = Ks[it & 1];
    const ushort* VsB = Vs[it & 1];

    // S^T for this wave's m-half: rows m = mtw*16 + quad*4+r, cols q = qg*32+qt*16+col
    floatx4 st[2];
    {
      int row = mtw * 16 + col;
      bf16x8 kf[4];
      #pragma unroll
      for (int kc = 0; kc < 4; ++kc)
        kf[kc] = *(const bf16x8*)&KsB[row * 128 + (((4 * kc + quad) ^ (col & 7)) * 8)];
      #pragma unroll
      for (int qt = 0; qt < 2; ++qt) {
        floatx4 acc = (floatx4)0.f;
        #pragma unroll
        for (int kc = 0; kc < 4; ++kc)
          acc = __builtin_amdgcn_mfma_f32_16x16x32_bf16(kf[kc], qf[qt][kc], acc, 0, 0, 0);
        st[qt] = acc;
      }
    }
    // no-max softmax: p = exp2(S) straight off the MFMA
    #pragma unroll
    for (int qt = 0; qt < 2; ++qt) {
      int prow = (qg * 32 + qt * 16 + col) * PLD + mtw * 16;
      float p0 = exp2f(st[qt][0]);
      float p1 = exp2f(st[qt][1]);
      float p2 = exp2f(st[qt][2]);
      float p3 = exp2f(st[qt][3]);
      uint2 pk = { pkbf(p1, p0), pkbf(p3, p2) };
      *(uint2*)&Ps[prow + quad * 4] = pk;
      lacc[qt] += (p0 + p1) + (p2 + p3);
    }
    __syncthreads();   // Ps complete (both m-halves) + staging vmcnt drained
    // PV: wave w owns q-half qh (4 q-tiles) x channels [cq*32, cq*32+32)
    bf16x8 vf[2];
    #pragma unroll
    for (int ct = 0; ct < 2; ++ct)
      vf[ct] = *(const bf16x8*)&VsB[(cq * 32 + ct * 16 + col) * MT + quad * 8];
    #pragma unroll
    for (int qt = 0; qt < 4; ++qt) {
      bf16x8 pf = *(const bf16x8*)&Ps[(qh * 64 + qt * 16 + col) * PLD + quad * 8];
      #pragma unroll
      for (int ct = 0; ct < 2; ++ct)
        Oacc[qt][ct] = __builtin_amdgcn_mfma_f32_16x16x32_bf16(pf, vf[ct], Oacc[qt][ct], 0, 0, 0);
    }
    __syncthreads();   // all waves done with Ps + Ks/Vs[cur] before overwrite
  }

  // epilogue: Op[sp][b][n][c] bf16 (unnormalized)
  ushort* OpB = Op + (((size_t)sp * B_ + b) * N_ + n0) * C_;
  #pragma unroll
  for (int qt = 0; qt < 4; ++qt)
    #pragma unroll
    for (int ct = 0; ct < 2; ++ct)
      #pragma unroll
      for (int r = 0; r < 4; ++r)
        OpB[(size_t)(qh * 64 + qt * 16 + quad * 4 + r) * C_ + cq * 32 + ct * 16 + col] =
            f2bf(Oacc[qt][ct][r]);
  // l: reduce within wave (over quads), then combine the two m-halves via LDS
  #pragma unroll
  for (int qt = 0; qt < 2; ++qt) {
    float lsum = lacc[qt];
    lsum += __shfl_xor(lsum, 16, 64);
    lsum += __shfl_xor(lsum, 32, 64);
    if (quad == 0) lpart[w][qt][col] = lsum;
  }
  __syncthreads();
  if ((w & 1) == 0 && quad == 0) {
    #pragma unroll
    for (int qt = 0; qt < 2; ++qt) {
      int idx = b * N_ + n0 + (w >> 1) * 32 + qt * 16 + col;
      Lv[(size_t)sp * (B_ * N_) + idx] = lpart[w][qt][col] + lpart[w + 1][qt][col];
    }
  }
}

// ---------------- fused merge(4 splits, no-max) + proj MFMA + residual ----------------
// grid 1024 = (b, 16-n tile); Op loads coalesced via LDS tile
__global__ __launch_bounds__(256) void mergeproj_kernel(
    const ushort* __restrict__ Op, const float* __restrict__ Lv,
    const ushort* __restrict__ wpB, const float* __restrict__ bp,
    const float* __restrict__ x, float* __restrict__ out) {
  __shared__ __align__(16) ushort tile[16 * HLD];
  int tid = threadIdx.x;
  int b = blockIdx.x >> 8;
  int n0 = (blockIdx.x & 255) * 16;
  {
    int n = tid >> 4, cc = tid & 15;
    int nIdx = b * N_ + n0 + n;
    float den = Lv[0 * (B_ * N_) + nIdx] + Lv[1 * (B_ * N_) + nIdx] +
                Lv[2 * (B_ * N_) + nIdx] + Lv[3 * (B_ * N_) + nIdx];
    float inv = 1.f / den;
    float o[8];
    #pragma unroll
    for (int j = 0; j < 8; ++j) o[j] = 0.f;
    #pragma unroll
    for (int sp = 0; sp < NSPLIT; ++sp) {
      uint4 d = *(const uint4*)&Op[((size_t)sp * (B_ * N_) + nIdx) * C_ + cc * 8];
      unsigned dd[4] = {d.x, d.y, d.z, d.w};
      #pragma unroll
      for (int j = 0; j < 4; ++j) {
        o[j * 2]     += bf2f((ushort)(dd[j] & 0xFFFF));
        o[j * 2 + 1] += bf2f((ushort)(dd[j] >> 16));
      }
    }
    uint4 res;
    res.x = pkbf(o[1] * inv, o[0] * inv);
    res.y = pkbf(o[3] * inv, o[2] * inv);
    res.z = pkbf(o[5] * inv, o[4] * inv);
    res.w = pkbf(o[7] * inv, o[6] * inv);
    *(uint4*)&tile[n * HLD + cc * 8] = res;
  }
  __syncthreads();
  int lane = tid & 63, w = tid >> 6;
  int col = lane & 15, quad = lane >> 4;
  int oh = w * 32;
  bf16x8 hf[4];
  #pragma unroll
  for (int kc = 0; kc < 4; ++kc)
    hf[kc] = *(const bf16x8*)&tile[col * HLD + kc * 32 + quad * 8];
  #pragma unroll
  for (int ot = 0; ot < 2; ++ot) {
    int o0 = oh + ot * 16;
    floatx4 acc = (floatx4)0.f;
    #pragma unroll
    for (int kc = 0; kc < 4; ++kc) {
      int wo = (o0 + col) * C_ + kc * 32 + quad * 8;
      acc = __builtin_amdgcn_mfma_f32_16x16x32_bf16(*(const bf16x8*)&wpB[wo], hf[kc], acc, 0, 0, 0);
    }
    float4 bpv = *(const float4*)&bp[o0 + quad * 4];
    float bb[4] = {bpv.x, bpv.y, bpv.z, bpv.w};
    #pragma unroll
    for (int r = 0; r < 4; ++r) {
      size_t idx = ((size_t)b * C_ + o0 + quad * 4 + r) * N_ + n0 + col;
      out[idx] = acc[r] + bb[r] + x[idx];
    }
  }
}

extern "C" void kernel_launch(void* const* d_in, const int* in_sizes, int n_in,
                              void* d_out, int out_size, void* d_ws, size_t ws_size,
                              hipStream_t stream) {
  const float* x        = (const float*)d_in[0];
  const float* gn_scale = (const float*)d_in[1];
  const float* gn_bias  = (const float*)d_in[2];
  const float* wq = (const float*)d_in[3];
  const float* bq = (const float*)d_in[4];
  const float* wk = (const float*)d_in[5];
  const float* bk = (const float*)d_in[6];
  const float* wv = (const float*)d_in[7];
  const float* bv = (const float*)d_in[8];
  const float* wp = (const float*)d_in[9];
  const float* bp = (const float*)d_in[10];
  float* out = (float*)d_out;

  char* ws = (char*)d_ws;
  float*  Lv    = (float*)(ws + 262144);
  ushort* wB    = (ushort*)(ws + 524288);
  float*  gstat = (float*)(ws + 655360);
  ushort* qT    = (ushort*)(ws + (4u << 20));
  ushort* kT    = (ushort*)(ws + (8u << 20));
  ushort* vB    = (ushort*)(ws + (12u << 20));
  ushort* Op    = (ushort*)(ws + (16u << 20));
  ushort* wpB   = wB + 49152;

  prep_kernel<<<512, 256, 0, stream>>>(x, gstat, wq, wk, wv, wp, wB);
  gnqkv_kernel<<<1024, 256, 0, stream>>>(x, gstat, gn_scale, gn_bias, wB, bq, bk, bv, qT, kT, vB);
  attn_kernel<<<512, 512, 0, stream>>>(qT, kT, vB, Op, Lv);
  mergeproj_kernel<<<1024, 256, 0, stream>>>(Op, Lv, wpB, bp, x, out);
}